// Round 2
// baseline (1147.523 us; speedup 1.0000x reference)
//
#include <hip/hip_runtime.h>
#include <hip/hip_bf16.h>
#include <math.h>

#define NB 4
#define LL 512
#define FF 128
#define CC 64
#define HH 12
#define DQi 32
#define PP 8
#define HD 384    // H*DQ = H*DV
#define HP3 288   // H*P*3
#define DIN 1824
#define NROW (NB*LL)

// ---------------- K1: projections ----------------
__global__ __launch_bounds__(256) void k_proj(
    const float* __restrict__ x, const float* __restrict__ R, const float* __restrict__ coord,
    const float* __restrict__ Wq, const float* __restrict__ Wk, const float* __restrict__ Wv,
    const float* __restrict__ Wqp, const float* __restrict__ Wkp, const float* __restrict__ Wvp,
    float* __restrict__ q, float* __restrict__ k, float* __restrict__ v,
    float* __restrict__ qp, float* __restrict__ kp, float* __restrict__ vp)
{
  const int RB = 8;
  int row0 = blockIdx.x * RB;
  int t = threadIdx.x;
  __shared__ float xs[8][FF];
  __shared__ float pl[8][3*HP3];
  for (int idx = t; idx < RB*FF/4; idx += 256) {
    int r = idx / 32, s = idx % 32;
    ((float4*)xs[r])[s] = ((const float4*)&x[(size_t)(row0+r)*FF])[s];
  }
  __syncthreads();
  for (int c = t; c < HD; c += 256) {
    float aq[8], ak[8], av[8];
    #pragma unroll
    for (int r=0;r<RB;++r){aq[r]=0.f;ak[r]=0.f;av[r]=0.f;}
    for (int f = 0; f < FF; ++f) {
      float wq = Wq[f*HD+c], wk = Wk[f*HD+c], wv = Wv[f*HD+c];
      #pragma unroll
      for (int r=0;r<RB;++r){ float xv=xs[r][f]; aq[r]+=xv*wq; ak[r]+=xv*wk; av[r]+=xv*wv; }
    }
    for (int r=0;r<RB;++r){ size_t o=(size_t)(row0+r)*HD+c; q[o]=aq[r]; k[o]=ak[r]; v[o]=av[r]; }
  }
  for (int c = t; c < HP3; c += 256) {
    float a0[8], a1[8], a2[8];
    #pragma unroll
    for (int r=0;r<RB;++r){a0[r]=0.f;a1[r]=0.f;a2[r]=0.f;}
    for (int f=0; f<FF; ++f) {
      float w0=Wqp[f*HP3+c], w1=Wkp[f*HP3+c], w2=Wvp[f*HP3+c];
      #pragma unroll
      for (int r=0;r<RB;++r){ float xv=xs[r][f]; a0[r]+=xv*w0; a1[r]+=xv*w1; a2[r]+=xv*w2; }
    }
    for (int r=0;r<RB;++r){ pl[r][c]=a0[r]; pl[r][HP3+c]=a1[r]; pl[r][2*HP3+c]=a2[r]; }
  }
  __syncthreads();
  for (int idx = t; idx < RB*3*96; idx += 256) {
    int r = idx / 288; int rem = idx % 288; int which = rem / 96; int m = rem % 96;
    int row = row0 + r;
    const float* Rl = &R[(size_t)row*9];
    float cx = coord[(size_t)row*3+0], cy = coord[(size_t)row*3+1], cz = coord[(size_t)row*3+2];
    const float* p = &pl[r][which*HP3 + m*3];
    float gg0 = Rl[0]*p[0]+Rl[1]*p[1]+Rl[2]*p[2]+cx;
    float gg1 = Rl[3]*p[0]+Rl[4]*p[1]+Rl[5]*p[2]+cy;
    float gg2 = Rl[6]*p[0]+Rl[7]*p[1]+Rl[8]*p[2]+cz;
    float* dst = which==0?qp:(which==1?kp:vp);
    size_t o = (size_t)row*HP3 + m*3;
    dst[o]=gg0; dst[o+1]=gg1; dst[o+2]=gg2;
  }
}

// ---------------- K2: logits + online softmax stats ----------------
#define IB2 4
#define JC2 16
__global__ __launch_bounds__(256) void k_logits(
    const float* __restrict__ qg, const float* __restrict__ kg,
    const float* __restrict__ qpg, const float* __restrict__ kpg,
    const float* __restrict__ pf, const float* __restrict__ Wpb, const float* __restrict__ sc,
    float* __restrict__ logits, float* __restrict__ m_buf, float* __restrict__ s_buf)
{
  int b = blockIdx.x;
  int n = b / (LL/IB2); int i0 = (b % (LL/IB2)) * IB2;
  int t = threadIdx.x;
  __shared__ float qi[IB2*HH*33];
  __shared__ float qpi[IB2*HH*25];
  __shared__ float wpbs[CC*HH];
  __shared__ float pfs[IB2*JC2*68];
  __shared__ float coefs[HH];
  for (int idx = t; idx < IB2*HD; idx += 256) {
    int ii = idx / HD; int c = idx % HD; int h = c/DQi, d=c%DQi;
    qi[(ii*HH+h)*33+d] = qg[(size_t)(n*LL+i0+ii)*HD + c];
  }
  for (int idx = t; idx < IB2*HP3; idx += 256) {
    int ii = idx / HP3; int c = idx % HP3; int h = c/24, e=c%24;
    qpi[(ii*HH+h)*25+e] = qpg[(size_t)(n*LL+i0+ii)*HP3 + c];
  }
  for (int idx = t; idx < CC*HH; idx += 256) wpbs[idx] = Wpb[idx];
  if (t < HH) coefs[t] = -log1pf(__expf(sc[t])) * (1.0f/12.0f);
  __syncthreads();
  int jj = t % JC2, h = t / JC2;
  bool active = t < JC2*HH;
  float wreg[CC];
  float coef_h = 0.f;
  if (active) {
    #pragma unroll
    for (int c=0;c<CC;++c) wreg[c]=wpbs[c*HH+h];
    coef_h = coefs[h];
  }
  float m[IB2], s[IB2];
  #pragma unroll
  for (int ii=0;ii<IB2;++ii){ m[ii]=-1e30f; s[ii]=0.f; }
  for (int j0 = 0; j0 < LL; j0 += JC2) {
    for (int idx = t; idx < IB2*JC2*16; idx += 256) {
      int ii = idx / (JC2*16); int rem = idx % (JC2*16); int jjj = rem/16; int c4 = rem%16;
      float4 vv = ((const float4*)&pf[(((size_t)(n*LL+i0+ii)*LL)+(size_t)(j0+jjj))*CC])[c4];
      *(float4*)&pfs[(ii*JC2+jjj)*68 + c4*4] = vv;
    }
    __syncthreads();
    if (active) {
      int j = j0 + jj;
      float kreg[DQi];
      { const float4* p4 = (const float4*)&kg[(size_t)(n*LL+j)*HD + h*DQi];
        #pragma unroll
        for (int w=0;w<8;++w){ float4 vv=p4[w]; kreg[4*w]=vv.x;kreg[4*w+1]=vv.y;kreg[4*w+2]=vv.z;kreg[4*w+3]=vv.w; } }
      float kpreg[24];
      { const float4* p4 = (const float4*)&kpg[(size_t)(n*LL+j)*HP3 + h*24];
        #pragma unroll
        for (int w=0;w<6;++w){ float4 vv=p4[w]; kpreg[4*w]=vv.x;kpreg[4*w+1]=vv.y;kpreg[4*w+2]=vv.z;kpreg[4*w+3]=vv.w; } }
      #pragma unroll
      for (int ii=0;ii<IB2;++ii) {
        const float* qh = &qi[(ii*HH+h)*33];
        float node=0.f;
        #pragma unroll
        for (int d=0;d<DQi;++d) node += qh[d]*kreg[d];
        const float* qph = &qpi[(ii*HH+h)*25];
        float ssd=0.f;
        #pragma unroll
        for (int e=0;e<24;++e){ float df=qph[e]-kpreg[e]; ssd+=df*df; }
        const float* pfr = &pfs[(ii*JC2+jj)*68];
        float pv=0.f;
        #pragma unroll
        for (int c=0;c<CC;++c) pv += pfr[c]*wreg[c];
        float lg = (node*0.17677669529663687f + pv + ssd*coef_h)*0.5773502691896258f;
        logits[(((size_t)(n*LL+i0+ii)*LL)+(size_t)j)*HH + h] = lg;
        if (lg > m[ii]) { s[ii] = s[ii]*__expf(m[ii]-lg) + 1.0f; m[ii]=lg; }
        else s[ii] += __expf(lg-m[ii]);
      }
    }
    __syncthreads();
  }
  if (active) {
    #pragma unroll
    for (int ii=0;ii<IB2;++ii) {
      float mm = m[ii], ss = s[ii];
      #pragma unroll
      for (int o=1;o<16;o<<=1) {
        float m2 = __shfl_xor(mm, o);
        float s2 = __shfl_xor(ss, o);
        float mn = fmaxf(mm, m2);
        ss = ss*__expf(mm-mn) + s2*__expf(m2-mn);
        mm = mn;
      }
      if (jj == 0) {
        m_buf[(size_t)(n*LL+i0+ii)*HH + h] = mm;
        s_buf[(size_t)(n*LL+i0+ii)*HH + h] = ss;
      }
    }
  }
}

// ---------------- K3: alpha + weighted accumulations + feat_all ----------------
#define IB3 4
#define JC3 16
#define AOFF (IB3*JC3*68)   // 4352
__global__ __launch_bounds__(256) void k_accum(
    const float* __restrict__ pf, const float* __restrict__ vg, const float* __restrict__ vpg,
    const float* __restrict__ logits, const float* __restrict__ m_buf, const float* __restrict__ s_buf,
    const float* __restrict__ R, const float* __restrict__ coord,
    float* __restrict__ feat_all)
{
  int b = blockIdx.x; int n = b/(LL/IB3); int i0 = (b%(LL/IB3))*IB3;
  int t = threadIdx.x;
  __shared__ float smem[IB3*1440];   // union: [pfs 4352 | alpha 768] then accbuf 5760
  __shared__ float ms[IB3*HH], invs[IB3*HH];
  for (int idx=t; idx<IB3*HH; idx+=256) {
    int ii = idx/HH, h = idx%HH;
    ms[idx]   = m_buf[(size_t)(n*LL+i0+ii)*HH + h];
    invs[idx] = 1.0f / s_buf[(size_t)(n*LL+i0+ii)*HH + h];
  }
  float acc[6][IB3];
  #pragma unroll
  for (int qq=0;qq<6;++qq)
    #pragma unroll
    for (int ii=0;ii<IB3;++ii) acc[qq][ii]=0.f;
  __syncthreads();
  for (int j0=0;j0<LL;j0+=JC3) {
    for (int idx = t; idx < IB3*JC3*16; idx += 256) {
      int ii = idx / (JC3*16); int rem = idx % (JC3*16); int jjj = rem/16; int c4 = rem%16;
      float4 vv = ((const float4*)&pf[(((size_t)(n*LL+i0+ii)*LL)+(size_t)(j0+jjj))*CC])[c4];
      *(float4*)&smem[(ii*JC3+jjj)*68 + c4*4] = vv;
    }
    __syncthreads();  // pfs staged; alpha region written next by subset
    if (t < JC3*HH) {
      int jj=t%JC3, h=t/JC3; int j=j0+jj;
      #pragma unroll
      for (int ii=0;ii<IB3;++ii) {
        float lg = logits[(((size_t)(n*LL+i0+ii)*LL)+(size_t)j)*HH+h];
        smem[AOFF + (ii*JC3+jj)*HH + h] = __expf(lg - ms[ii*HH+h]) * invs[ii*HH+h];
      }
    }
    __syncthreads();
    #pragma unroll
    for (int qq=0;qq<6;++qq) {
      int e = t + qq*256; if (e>=1440) break;
      int h = e/120, r = e%120;
      if (r < 64) {
        for (int jj=0;jj<JC3;++jj) {
          #pragma unroll
          for (int ii=0;ii<IB3;++ii)
            acc[qq][ii] += smem[AOFF+(ii*JC3+jj)*HH+h] * smem[(ii*JC3+jj)*68 + r];
        }
      } else if (r < 96) {
        int d = r-64;
        for (int jj=0;jj<JC3;++jj) {
          float vv = vg[(size_t)(n*LL+j0+jj)*HD + h*DQi + d];
          #pragma unroll
          for (int ii=0;ii<IB3;++ii) acc[qq][ii] += smem[AOFF+(ii*JC3+jj)*HH+h]*vv;
        }
      } else {
        int rr = r-96;
        for (int jj=0;jj<JC3;++jj) {
          float vv = vpg[(size_t)(n*LL+j0+jj)*HP3 + h*24 + rr];
          #pragma unroll
          for (int ii=0;ii<IB3;++ii) acc[qq][ii] += smem[AOFF+(ii*JC3+jj)*HH+h]*vv;
        }
      }
    }
    __syncthreads();
  }
  // dump accumulators to smem
  #pragma unroll
  for (int qq=0;qq<6;++qq){
    int e=t+qq*256;
    if (e<1440) {
      #pragma unroll
      for (int ii=0;ii<IB3;++ii) smem[ii*1440+e]=acc[qq][ii];
    }
  }
  __syncthreads();
  // feat_pair + feat_node
  for (int idx=t; idx<IB3*1152; idx+=256) {
    int ii = idx/1152, r2 = idx%1152;
    float val;
    if (r2<768){ int h=r2/64, c=r2%64; val = smem[ii*1440 + h*120 + c]; }
    else { int r3=r2-768; int h=r3/32, d=r3%32; val = smem[ii*1440 + h*120+64+d]; }
    feat_all[(size_t)(n*LL+i0+ii)*DIN + r2] = val;
  }
  // spatial: pts, dist, direc
  for (int idx=t; idx<IB3*96; idx+=256) {
    int ii = idx/96, mI = idx%96; int h=mI/8, p=mI%8;
    int row = n*LL+i0+ii;
    const float* Rl=&R[(size_t)row*9];
    float X0 = smem[ii*1440 + h*120+96 + p*3+0] - coord[(size_t)row*3+0];
    float X1 = smem[ii*1440 + h*120+96 + p*3+1] - coord[(size_t)row*3+1];
    float X2 = smem[ii*1440 + h*120+96 + p*3+2] - coord[(size_t)row*3+2];
    float p0 = Rl[0]*X0 + Rl[3]*X1 + Rl[6]*X2;
    float p1 = Rl[1]*X0 + Rl[4]*X1 + Rl[7]*X2;
    float p2 = Rl[2]*X0 + Rl[5]*X1 + Rl[8]*X2;
    float dist = sqrtf(p0*p0+p1*p1+p2*p2);
    float inv = 1.0f/(dist+1e-4f);
    size_t base = (size_t)row*DIN;
    feat_all[base+1152+mI*3+0]=p0;
    feat_all[base+1152+mI*3+1]=p1;
    feat_all[base+1152+mI*3+2]=p2;
    feat_all[base+1440+mI]=dist;
    feat_all[base+1536+mI*3+0]=p0*inv;
    feat_all[base+1536+mI*3+1]=p1*inv;
    feat_all[base+1536+mI*3+2]=p2*inv;
  }
}

// ---------------- K4: out-projection GEMM + residual + LN1 ----------------
__global__ __launch_bounds__(256) void k_outproj(
   const float* __restrict__ feat_all, const float* __restrict__ x,
   const float* __restrict__ Wout, const float* __restrict__ bout,
   const float* __restrict__ g1, const float* __restrict__ b1,
   float* __restrict__ x1)
{
  int row0 = blockIdx.x * 16;
  int t = threadIdx.x;
  __shared__ float Ws[96*128];
  __shared__ float fas[16*96];
  int c = t % 128, rr = t / 128;
  float acc[8];
  #pragma unroll
  for (int k2=0;k2<8;++k2) acc[k2]=0.f;
  for (int kc = 0; kc < DIN; kc += 96) {
    for (int idx=t; idx<96*128/4; idx+=256)
      ((float4*)Ws)[idx] = ((const float4*)&Wout[(size_t)kc*128])[idx];
    for (int idx=t; idx<16*24; idx+=256) {
      int r = idx/24, s4 = idx%24;
      ((float4*)&fas[r*96])[s4] = ((const float4*)&feat_all[(size_t)(row0+r)*DIN + kc])[s4];
    }
    __syncthreads();
    for (int kk=0; kk<96; ++kk) {
      float wv = Ws[kk*128 + c];
      #pragma unroll
      for (int k2=0;k2<8;++k2) acc[k2] += fas[(rr+2*k2)*96+kk]*wv;
    }
    __syncthreads();
  }
  float* ybuf = Ws;
  float bo = bout[c];
  #pragma unroll
  for (int k2=0;k2<8;++k2) {
    int r = rr + 2*k2;
    ybuf[r*128 + c] = acc[k2] + x[(size_t)(row0+r)*128 + c] + bo;
  }
  __syncthreads();
  int wv_ = t/64, lane = t%64;
  for (int r = wv_; r < 16; r += 4) {
    float y0 = ybuf[r*128+lane], y1 = ybuf[r*128+lane+64];
    float sum = y0+y1;
    #pragma unroll
    for (int o=1;o<64;o<<=1) sum += __shfl_xor(sum,o);
    float mean = sum * (1.0f/128.0f);
    float d0=y0-mean, d1=y1-mean;
    float vs = d0*d0+d1*d1;
    #pragma unroll
    for (int o=1;o<64;o<<=1) vs += __shfl_xor(vs,o);
    float rstd = rsqrtf(vs*(1.0f/128.0f)+1e-5f);
    x1[(size_t)(row0+r)*128+lane]    = d0*rstd*g1[lane]+b1[lane];
    x1[(size_t)(row0+r)*128+lane+64] = d1*rstd*g1[lane+64]+b1[lane+64];
  }
}

// ---------------- K5: MLP (3 layers) + residual + LN2 ----------------
__global__ __launch_bounds__(256) void k_mlp(
  const float* __restrict__ x1g,
  const float* __restrict__ Wm1,const float* __restrict__ bm1,
  const float* __restrict__ Wm2,const float* __restrict__ bm2,
  const float* __restrict__ Wm3,const float* __restrict__ bm3,
  const float* __restrict__ g2, const float* __restrict__ b2,
  float* __restrict__ out)
{
  int row0 = blockIdx.x*16;
  int t = threadIdx.x;
  __shared__ float x1s[16*128];
  __shared__ float bufA[16*128];
  __shared__ float bufB[16*128];
  __shared__ float Ws[64*128];
  for (int idx=t; idx<16*32; idx+=256)
    ((float4*)x1s)[idx] = ((const float4*)&x1g[(size_t)row0*128])[idx];
  __syncthreads();
  int c=t%128, rr=t/128;
  const float* in = x1s;
  for (int s=0;s<3;++s) {
    const float* Wcur = (s==0)?Wm1:((s==1)?Wm2:Wm3);
    const float* bcur = (s==0)?bm1:((s==1)?bm2:bm3);
    float acc[8];
    #pragma unroll
    for (int k2=0;k2<8;++k2) acc[k2]=0.f;
    for (int kc=0;kc<128;kc+=64) {
      for (int idx=t; idx<64*32; idx+=256)
        ((float4*)Ws)[idx]=((const float4*)&Wcur[(size_t)kc*128])[idx];
      __syncthreads();
      for (int kk=0;kk<64;++kk) {
        float wv=Ws[kk*128+c];
        #pragma unroll
        for (int k2=0;k2<8;++k2) acc[k2] += in[(rr+2*k2)*128 + kc+kk]*wv;
      }
      __syncthreads();
    }
    float bb = bcur[c];
    float* outb = (s%2==0) ? bufA : bufB;
    #pragma unroll
    for (int k2=0;k2<8;++k2) {
      float yv = acc[k2]+bb;
      if (s<2) yv = fmaxf(yv,0.f);
      outb[(rr+2*k2)*128+c]=yv;
    }
    __syncthreads();
    in = outb;
  }
  int wv_=t/64, lane=t%64;
  for (int r=wv_; r<16; r+=4) {
    float y0 = x1s[r*128+lane]+bufA[r*128+lane];
    float y1 = x1s[r*128+lane+64]+bufA[r*128+lane+64];
    float sum = y0+y1;
    #pragma unroll
    for (int o=1;o<64;o<<=1) sum += __shfl_xor(sum,o);
    float mean = sum * (1.0f/128.0f);
    float d0=y0-mean, d1=y1-mean;
    float vs = d0*d0+d1*d1;
    #pragma unroll
    for (int o=1;o<64;o<<=1) vs += __shfl_xor(vs,o);
    float rstd = rsqrtf(vs*(1.0f/128.0f)+1e-5f);
    out[(size_t)(row0+r)*128+lane]    = d0*rstd*g2[lane]+b2[lane];
    out[(size_t)(row0+r)*128+lane+64] = d1*rstd*g2[lane+64]+b2[lane+64];
  }
}

extern "C" void kernel_launch(void* const* d_in, const int* in_sizes, int n_in,
                              void* d_out, int out_size, void* d_ws, size_t ws_size,
                              hipStream_t stream) {
  const float* R     = (const float*)d_in[0];
  const float* coord = (const float*)d_in[1];
  const float* x     = (const float*)d_in[2];
  const float* pf    = (const float*)d_in[3];
  // d_in[4] = mask (all true in this problem) -- unused
  const float* Wq    = (const float*)d_in[5];
  const float* Wk    = (const float*)d_in[6];
  const float* Wv    = (const float*)d_in[7];
  const float* Wpb   = (const float*)d_in[8];
  const float* sc    = (const float*)d_in[9];
  const float* Wqp   = (const float*)d_in[10];
  const float* Wkp   = (const float*)d_in[11];
  const float* Wvp   = (const float*)d_in[12];
  const float* Wout  = (const float*)d_in[13];
  const float* bout  = (const float*)d_in[14];
  const float* Wm1   = (const float*)d_in[15];
  const float* bm1   = (const float*)d_in[16];
  const float* Wm2   = (const float*)d_in[17];
  const float* bm2   = (const float*)d_in[18];
  const float* Wm3   = (const float*)d_in[19];
  const float* bm3   = (const float*)d_in[20];
  const float* g1    = (const float*)d_in[21];
  const float* b1    = (const float*)d_in[22];
  const float* g2    = (const float*)d_in[23];
  const float* b2    = (const float*)d_in[24];

  float* ws = (float*)d_ws;
  float* q        = ws;                    // 2048*384
  float* k        = q + 786432;
  float* v        = k + 786432;
  float* qp       = v + 786432;            // 2048*288
  float* kp       = qp + 589824;
  float* vp       = kp + 589824;
  float* logits   = vp + 589824;           // 2048*512*12 = 12,582,912
  float* m_buf    = logits + 12582912;     // 2048*12
  float* s_buf    = m_buf + 24576;
  float* feat_all = s_buf + 24576;         // 2048*1824
  float* x1       = feat_all + 3735552;    // 2048*128
  float* out      = (float*)d_out;

  k_proj<<<dim3(NROW/8), dim3(256), 0, stream>>>(x,R,coord,Wq,Wk,Wv,Wqp,Wkp,Wvp,q,k,v,qp,kp,vp);
  k_logits<<<dim3(NROW/IB2), dim3(256), 0, stream>>>(q,k,qp,kp,pf,Wpb,sc,logits,m_buf,s_buf);
  k_accum<<<dim3(NROW/IB3), dim3(256), 0, stream>>>(pf,v,vp,logits,m_buf,s_buf,R,coord,feat_all);
  k_outproj<<<dim3(NROW/16), dim3(256), 0, stream>>>(feat_all,x,Wout,bout,g1,b1,x1);
  k_mlp<<<dim3(NROW/16), dim3(256), 0, stream>>>(x1,Wm1,bm1,Wm2,bm2,Wm3,bm3,g2,b2,out);
}

// Round 3
// 474.221 us; speedup vs baseline: 2.4198x; 2.4198x over previous
//
#include <hip/hip_runtime.h>
#include <hip/hip_bf16.h>
#include <math.h>

#define NB 4
#define LL 512
#define FF 128
#define CC 64
#define HH 12
#define DQi 32
#define PP 8
#define HD 384
#define HP3 288
#define DIN 1824
#define NROW (NB*LL)

typedef __attribute__((ext_vector_type(8))) short bf16x8;
typedef __attribute__((ext_vector_type(4))) float f32x4;

__device__ inline unsigned short f2b(float x){
  unsigned int u = __float_as_uint(x);
  unsigned int r = (u + 0x7FFFu + ((u>>16)&1u)) >> 16;
  return (unsigned short)r;
}

// ---------------- K1: projections (unchanged) ----------------
__global__ __launch_bounds__(256) void k_proj(
    const float* __restrict__ x, const float* __restrict__ R, const float* __restrict__ coord,
    const float* __restrict__ Wq, const float* __restrict__ Wk, const float* __restrict__ Wv,
    const float* __restrict__ Wqp, const float* __restrict__ Wkp, const float* __restrict__ Wvp,
    float* __restrict__ q, float* __restrict__ k, float* __restrict__ v,
    float* __restrict__ qp, float* __restrict__ kp, float* __restrict__ vp)
{
  const int RB = 8;
  int row0 = blockIdx.x * RB;
  int t = threadIdx.x;
  __shared__ float xs[8][FF];
  __shared__ float pl[8][3*HP3];
  for (int idx = t; idx < RB*FF/4; idx += 256) {
    int r = idx / 32, s = idx % 32;
    ((float4*)xs[r])[s] = ((const float4*)&x[(size_t)(row0+r)*FF])[s];
  }
  __syncthreads();
  for (int c = t; c < HD; c += 256) {
    float aq[8], ak[8], av[8];
    #pragma unroll
    for (int r=0;r<RB;++r){aq[r]=0.f;ak[r]=0.f;av[r]=0.f;}
    for (int f = 0; f < FF; ++f) {
      float wq = Wq[f*HD+c], wk = Wk[f*HD+c], wv = Wv[f*HD+c];
      #pragma unroll
      for (int r=0;r<RB;++r){ float xv=xs[r][f]; aq[r]+=xv*wq; ak[r]+=xv*wk; av[r]+=xv*wv; }
    }
    for (int r=0;r<RB;++r){ size_t o=(size_t)(row0+r)*HD+c; q[o]=aq[r]; k[o]=ak[r]; v[o]=av[r]; }
  }
  for (int c = t; c < HP3; c += 256) {
    float a0[8], a1[8], a2[8];
    #pragma unroll
    for (int r=0;r<RB;++r){a0[r]=0.f;a1[r]=0.f;a2[r]=0.f;}
    for (int f=0; f<FF; ++f) {
      float w0=Wqp[f*HP3+c], w1=Wkp[f*HP3+c], w2=Wvp[f*HP3+c];
      #pragma unroll
      for (int r=0;r<RB;++r){ float xv=xs[r][f]; a0[r]+=xv*w0; a1[r]+=xv*w1; a2[r]+=xv*w2; }
    }
    for (int r=0;r<RB;++r){ pl[r][c]=a0[r]; pl[r][HP3+c]=a1[r]; pl[r][2*HP3+c]=a2[r]; }
  }
  __syncthreads();
  for (int idx = t; idx < RB*3*96; idx += 256) {
    int r = idx / 288; int rem = idx % 288; int which = rem / 96; int m = rem % 96;
    int row = row0 + r;
    const float* Rl = &R[(size_t)row*9];
    float cx = coord[(size_t)row*3+0], cy = coord[(size_t)row*3+1], cz = coord[(size_t)row*3+2];
    const float* p = &pl[r][which*HP3 + m*3];
    float gg0 = Rl[0]*p[0]+Rl[1]*p[1]+Rl[2]*p[2]+cx;
    float gg1 = Rl[3]*p[0]+Rl[4]*p[1]+Rl[5]*p[2]+cy;
    float gg2 = Rl[6]*p[0]+Rl[7]*p[1]+Rl[8]*p[2]+cz;
    float* dst = which==0?qp:(which==1?kp:vp);
    size_t o = (size_t)row*HP3 + m*3;
    dst[o]=gg0; dst[o+1]=gg1; dst[o+2]=gg2;
  }
}

// ---------------- K1b: pack to bf16 MFMA-friendly layouts ----------------
// Arow[row][h][64]: [q*c1c3 (32) | qp*(-2*coef_h*c3) (24) | 0 (8)]
// Bvec[row][h][64]: [k (32) | kp (24) | 0]
// kpn[row][h] = coef_h*c3*|kp|^2
// Vcat[n][h][64][512]: d<32: v, d<56: vp, else 0   (j contiguous)
// WpbT[16][64]: c3*Wpb^T, rows h>=12 zero
__global__ __launch_bounds__(256) void k_pack(
  const float* __restrict__ q, const float* __restrict__ k, const float* __restrict__ v,
  const float* __restrict__ qp, const float* __restrict__ kp, const float* __restrict__ vp,
  const float* __restrict__ sc, const float* __restrict__ Wpb,
  unsigned short* __restrict__ Arow, unsigned short* __restrict__ Bvec,
  float* __restrict__ kpn, unsigned short* __restrict__ Vcat, unsigned short* __restrict__ WpbT)
{
  const float C3 = 0.57735026918962576f;
  const float C1C3 = 0.17677669529663687f * C3;
  int row0 = blockIdx.x * 8;
  int t = threadIdx.x;
  for (int idx = t; idx < 8*768; idx += 256) {
    int lr = idx / 768; int rem = idx % 768; int h = rem >> 6; int d = rem & 63;
    int row = row0 + lr;
    float cof = -log1pf(__expf(sc[h])) * (1.0f/12.0f);
    float av, bv;
    if (d < 32) { av = q[(size_t)row*HD + h*32 + d] * C1C3; bv = k[(size_t)row*HD + h*32 + d]; }
    else if (d < 56) { int e = d-32;
      av = qp[(size_t)row*HP3 + h*24 + e] * (-2.0f*cof*C3);
      bv = kp[(size_t)row*HP3 + h*24 + e]; }
    else { av = 0.f; bv = 0.f; }
    Arow[(size_t)row*768 + rem] = f2b(av);
    Bvec[(size_t)row*768 + rem] = f2b(bv);
  }
  for (int idx = t; idx < 96; idx += 256) {
    int lr = idx / 12, h = idx % 12; int row = row0 + lr;
    float cof = -log1pf(__expf(sc[h])) * (1.0f/12.0f);
    float ss = 0.f;
    for (int e=0;e<24;++e){ float vv = kp[(size_t)row*HP3 + h*24 + e]; ss += vv*vv; }
    kpn[(size_t)row*12 + h] = cof * C3 * ss;
  }
  int n = row0 >> 9; int j0l = row0 & 511;
  for (int idx = t; idx < 768; idx += 256) {
    int h = idx >> 6, d = idx & 63;
    unsigned short tmp[8];
    for (int lr=0; lr<8; ++lr) {
      float vv;
      if (d < 32) vv = v[(size_t)(row0+lr)*HD + h*32 + d];
      else if (d < 56) vv = vp[(size_t)(row0+lr)*HP3 + h*24 + (d-32)];
      else vv = 0.f;
      tmp[lr] = f2b(vv);
    }
    uint4 pk;
    pk.x = (unsigned)tmp[0] | ((unsigned)tmp[1]<<16);
    pk.y = (unsigned)tmp[2] | ((unsigned)tmp[3]<<16);
    pk.z = (unsigned)tmp[4] | ((unsigned)tmp[5]<<16);
    pk.w = (unsigned)tmp[6] | ((unsigned)tmp[7]<<16);
    *(uint4*)&Vcat[(((size_t)n*12 + h)*64 + d)*512 + j0l] = pk;
  }
  if (blockIdx.x == 0) {
    for (int idx = t; idx < 16*64; idx += 256) {
      int h = idx >> 6, c = idx & 63;
      WpbT[idx] = (h < HH) ? f2b(Wpb[c*HH + h] * C3) : (unsigned short)0;
    }
  }
}

// ---------------- K2: fused logits+softmax+accumulate (flash-style, MFMA) ----------------
// grid: 256 blocks = n(4) x ib(32) x jh(2); 256 threads (4 waves)
// LDS: pftile bf16 [16 i][64 c][40 j-pad]  (transposed pf tile, j-tile=32)
//      W1 bf16 [16 h][16 i][40 j-pad]  (exp weights, for A of node/vp GEMM)
//      W2 bf16 [16 i][16 h][40 j-pad]  (for A of pair GEMM)
//      lg f32 [i*417 + j*13 + h]
//      kpn_s f32 [32][12]
#define LGI(i,j,h) ((i)*417 + (j)*13 + (h))
extern "C" __global__ void __launch_bounds__(256,1) k_attn(
  const float* __restrict__ pf, const unsigned short* __restrict__ Arow,
  const unsigned short* __restrict__ Bvec, const unsigned short* __restrict__ Vcat,
  const unsigned short* __restrict__ WpbT, const float* __restrict__ kpn,
  float* __restrict__ accNV, float* __restrict__ accP, float* __restrict__ s_part)
{
  extern __shared__ char smem_raw[];
  unsigned short* pftile = (unsigned short*)smem_raw;       // 40960 shorts
  unsigned short* W1 = pftile + 40960;                      // 10240
  unsigned short* W2 = W1 + 10240;                          // 10240
  float* lg = (float*)(smem_raw + 122880);                  // 6672 floats
  float* kpn_s = lg + 6672;                                 // 384 floats

  int b = blockIdx.x;
  int jh = b & 1; int ib = (b >> 1) & 31; int n = b >> 6;
  int i0 = ib * 16; int jbase = jh * 256;
  int t = threadIdx.x; int w = t >> 6; int l = t & 63;
  int l15 = l & 15, lg4 = l >> 4;

  // zero W1/W2 (rows h>=12 must stay zero forever)
  for (int idx = t; idx < 10240; idx += 256) ((unsigned*)W1)[idx] = 0u;
  __syncthreads();

  // persistent A fragments
  bf16x8 aAB[3][2];
  #pragma unroll
  for (int hh=0; hh<3; ++hh) {
    int h = 3*w + hh;
    #pragma unroll
    for (int ks=0; ks<2; ++ks)
      aAB[hh][ks] = *(const bf16x8*)&Arow[(size_t)(n*LL + i0 + l15)*768 + h*64 + ks*32 + lg4*8];
  }
  bf16x8 aPV[2];
  #pragma unroll
  for (int ks=0; ks<2; ++ks)
    aPV[ks] = *(const bf16x8*)&WpbT[l15*64 + ks*32 + lg4*8];

  f32x4 cNV[3][4]; f32x4 cP[4][4];
  #pragma unroll
  for (int a=0;a<3;++a)
    #pragma unroll
    for (int nt=0;nt<4;++nt) cNV[a][nt] = (f32x4){0.f,0.f,0.f,0.f};
  #pragma unroll
  for (int a=0;a<4;++a)
    #pragma unroll
    for (int nt=0;nt<4;++nt) cP[a][nt] = (f32x4){0.f,0.f,0.f,0.f};
  float s_acc = 0.f;
  int smi = t / 12, smh = t % 12;   // valid when t<192

  for (int jt = 0; jt < 8; ++jt) {
    int j0 = jbase + jt*32;
    // ---- stage: pf tile -> LDS transposed bf16; kpn slice ----
    {
      int si = t >> 4; int sj = (t & 15) * 2;
      const float* src0 = pf + (((size_t)(n*LL + i0 + si)*LL) + (j0 + sj))*CC;
      const float* src1 = src0 + CC;
      #pragma unroll
      for (int c4 = 0; c4 < 16; ++c4) {
        float4 va = ((const float4*)src0)[c4];
        float4 vb = ((const float4*)src1)[c4];
        int base = (si*64 + c4*4)*40 + sj;
        *(unsigned*)&pftile[base      ] = (unsigned)f2b(va.x) | ((unsigned)f2b(vb.x)<<16);
        *(unsigned*)&pftile[base + 40 ] = (unsigned)f2b(va.y) | ((unsigned)f2b(vb.y)<<16);
        *(unsigned*)&pftile[base + 80 ] = (unsigned)f2b(va.z) | ((unsigned)f2b(vb.z)<<16);
        *(unsigned*)&pftile[base + 120] = (unsigned)f2b(va.w) | ((unsigned)f2b(vb.w)<<16);
      }
      if (t < 96) ((float4*)kpn_s)[t] = ((const float4*)(kpn + (size_t)(n*LL + j0)*12))[t];
    }
    __syncthreads();
    // ---- phase L: AB logits via MFMA ----
    #pragma unroll
    for (int hh=0; hh<3; ++hh) {
      int h = 3*w + hh;
      f32x4 c0 = (f32x4){0.f,0.f,0.f,0.f}, c1 = (f32x4){0.f,0.f,0.f,0.f};
      #pragma unroll
      for (int ks=0; ks<2; ++ks) {
        bf16x8 b0 = *(const bf16x8*)&Bvec[(size_t)(n*LL + j0 + l15)*768 + h*64 + ks*32 + lg4*8];
        bf16x8 b1 = *(const bf16x8*)&Bvec[(size_t)(n*LL + j0 + 16 + l15)*768 + h*64 + ks*32 + lg4*8];
        c0 = __builtin_amdgcn_mfma_f32_16x16x32_bf16(aAB[hh][ks], b0, c0, 0,0,0);
        c1 = __builtin_amdgcn_mfma_f32_16x16x32_bf16(aAB[hh][ks], b1, c1, 0,0,0);
      }
      #pragma unroll
      for (int r=0;r<4;++r) {
        int i = lg4*4 + r;
        lg[LGI(i, l15, h)] = c0[r];
        lg[LGI(i, 16+l15, h)] = c1[r];
      }
    }
    __syncthreads();
    // ---- phase P: pv = pf @ WpbT, add into lg ----
    #pragma unroll
    for (int pt=0; pt<8; ++pt) {
      int p = 8*w + pt; int ii = p >> 1; int jloc = (p & 1)*16 + l15;
      f32x4 c = (f32x4){0.f,0.f,0.f,0.f};
      #pragma unroll
      for (int ks=0; ks<2; ++ks) {
        bf16x8 bb;
        int cb = ks*32 + lg4*8;
        #pragma unroll
        for (int e=0;e<8;++e) bb[e] = (short)pftile[(ii*64 + cb + e)*40 + jloc];
        c = __builtin_amdgcn_mfma_f32_16x16x32_bf16(aPV[ks], bb, c, 0,0,0);
      }
      #pragma unroll
      for (int r=0;r<4;++r) {
        int h = lg4*4 + r;
        if (h < HH) lg[LGI(ii, jloc, h)] += c[r];
      }
    }
    __syncthreads();
    // ---- phase SM: exp, write W tiles (bf16), accumulate s ----
    if (t < 192) {
      float partial = 0.f;
      #pragma unroll
      for (int j2=0; j2<32; j2+=2) {
        float e0 = __expf(lg[LGI(smi, j2, smh)] + kpn_s[j2*12 + smh]);
        float e1 = __expf(lg[LGI(smi, j2+1, smh)] + kpn_s[(j2+1)*12 + smh]);
        partial += e0 + e1;
        unsigned pk = (unsigned)f2b(e0) | ((unsigned)f2b(e1)<<16);
        *(unsigned*)&W1[(smh*16 + smi)*40 + j2] = pk;
        *(unsigned*)&W2[(smi*16 + smh)*40 + j2] = pk;
      }
      s_acc += partial;
    }
    __syncthreads();
    // ---- phase A: accumulate ----
    #pragma unroll
    for (int hh=0; hh<3; ++hh) {
      int h = 3*w + hh;
      bf16x8 aW = *(const bf16x8*)&W1[(h*16 + l15)*40 + lg4*8];
      #pragma unroll
      for (int nt=0; nt<4; ++nt) {
        bf16x8 bV = *(const bf16x8*)&Vcat[(((size_t)n*12 + h)*64 + nt*16 + l15)*512 + j0 + lg4*8];
        cNV[hh][nt] = __builtin_amdgcn_mfma_f32_16x16x32_bf16(aW, bV, cNV[hh][nt], 0,0,0);
      }
    }
    #pragma unroll
    for (int it=0; it<4; ++it) {
      int ii = 4*w + it;
      bf16x8 aW = *(const bf16x8*)&W2[(ii*16 + l15)*40 + lg4*8];
      #pragma unroll
      for (int nt=0; nt<4; ++nt) {
        bf16x8 bP = *(const bf16x8*)&pftile[(ii*64 + nt*16 + l15)*40 + lg4*8];
        cP[it][nt] = __builtin_amdgcn_mfma_f32_16x16x32_bf16(aW, bP, cP[it][nt], 0,0,0);
      }
    }
    __syncthreads();
  }
  // ---- epilogue: store partials ----
  if (t < 192) s_part[(size_t)b*192 + t] = s_acc;
  #pragma unroll
  for (int hh=0; hh<3; ++hh) {
    int h = 3*w + hh;
    #pragma unroll
    for (int nt=0; nt<4; ++nt)
      #pragma unroll
      for (int r=0;r<4;++r) {
        int ii = lg4*4 + r; int d = nt*16 + l15;
        accNV[((size_t)b*12 + h)*1024 + ii*64 + d] = cNV[hh][nt][r];
      }
  }
  #pragma unroll
  for (int it=0; it<4; ++it) {
    int ii = 4*w + it;
    #pragma unroll
    for (int nt=0; nt<4; ++nt)
      #pragma unroll
      for (int r=0;r<4;++r) {
        int h2 = lg4*4 + r; int cc = nt*16 + l15;
        accP[((size_t)b*16 + ii)*1024 + h2*64 + cc] = cP[it][nt][r];
      }
  }
}

// ---------------- K3: merge partials -> feat_all ----------------
__global__ __launch_bounds__(128) void k_merge(
  const float* __restrict__ accNV, const float* __restrict__ accP, const float* __restrict__ s_part,
  const float* __restrict__ R, const float* __restrict__ coord,
  float* __restrict__ feat_all)
{
  int r = blockIdx.x; int t = threadIdx.x;
  int n = r >> 9; int i = r & 511; int ib = i >> 4; int iloc = i & 15;
  int b0 = (n*32 + ib)*2; int b1 = b0 + 1;
  __shared__ float sden[12];
  __shared__ float aggr_s[288];
  if (t < 12) sden[t] = 1.0f / (s_part[(size_t)b0*192 + iloc*12 + t] + s_part[(size_t)b1*192 + iloc*12 + t]);
  __syncthreads();
  size_t fb = (size_t)r * DIN;
  for (int idx = t; idx < 768; idx += 128) {
    int h = idx >> 6, c = idx & 63;
    float vsum = accP[((size_t)b0*16 + iloc)*1024 + h*64 + c] + accP[((size_t)b1*16 + iloc)*1024 + h*64 + c];
    feat_all[fb + idx] = vsum * sden[h];
  }
  for (int idx = t; idx < 384; idx += 128) {
    int h = idx >> 5, d = idx & 31;
    float vsum = accNV[((size_t)b0*12 + h)*1024 + iloc*64 + d] + accNV[((size_t)b1*12 + h)*1024 + iloc*64 + d];
    feat_all[fb + 768 + idx] = vsum * sden[h];
  }
  for (int idx = t; idx < 288; idx += 128) {
    int h = idx / 24, e = idx % 24;
    float vsum = accNV[((size_t)b0*12 + h)*1024 + iloc*64 + 32 + e] + accNV[((size_t)b1*12 + h)*1024 + iloc*64 + 32 + e];
    aggr_s[idx] = vsum * sden[h];
  }
  __syncthreads();
  for (int idx = t; idx < 96; idx += 128) {
    int h = idx >> 3, p = idx & 7;
    const float* Rl = &R[(size_t)r*9];
    float X0 = aggr_s[h*24 + p*3 + 0] - coord[(size_t)r*3 + 0];
    float X1 = aggr_s[h*24 + p*3 + 1] - coord[(size_t)r*3 + 1];
    float X2 = aggr_s[h*24 + p*3 + 2] - coord[(size_t)r*3 + 2];
    float p0 = Rl[0]*X0 + Rl[3]*X1 + Rl[6]*X2;
    float p1 = Rl[1]*X0 + Rl[4]*X1 + Rl[7]*X2;
    float p2 = Rl[2]*X0 + Rl[5]*X1 + Rl[8]*X2;
    float dist = sqrtf(p0*p0 + p1*p1 + p2*p2);
    float inv = 1.0f / (dist + 1e-4f);
    feat_all[fb + 1152 + idx*3 + 0] = p0;
    feat_all[fb + 1152 + idx*3 + 1] = p1;
    feat_all[fb + 1152 + idx*3 + 2] = p2;
    feat_all[fb + 1440 + idx] = dist;
    feat_all[fb + 1536 + idx*3 + 0] = p0*inv;
    feat_all[fb + 1536 + idx*3 + 1] = p1*inv;
    feat_all[fb + 1536 + idx*3 + 2] = p2*inv;
  }
}

// ---------------- K4: out-projection GEMM + residual + LN1 ----------------
__global__ __launch_bounds__(256) void k_outproj(
   const float* __restrict__ feat_all, const float* __restrict__ x,
   const float* __restrict__ Wout, const float* __restrict__ bout,
   const float* __restrict__ g1, const float* __restrict__ b1,
   float* __restrict__ x1)
{
  int row0 = blockIdx.x * 16;
  int t = threadIdx.x;
  __shared__ float Ws[96*128];
  __shared__ float fas[16*96];
  int c = t % 128, rr = t / 128;
  float acc[8];
  #pragma unroll
  for (int k2=0;k2<8;++k2) acc[k2]=0.f;
  for (int kc = 0; kc < DIN; kc += 96) {
    for (int idx=t; idx<96*128/4; idx+=256)
      ((float4*)Ws)[idx] = ((const float4*)&Wout[(size_t)kc*128])[idx];
    for (int idx=t; idx<16*24; idx+=256) {
      int r = idx/24, s4 = idx%24;
      ((float4*)&fas[r*96])[s4] = ((const float4*)&feat_all[(size_t)(row0+r)*DIN + kc])[s4];
    }
    __syncthreads();
    for (int kk=0; kk<96; ++kk) {
      float wv = Ws[kk*128 + c];
      #pragma unroll
      for (int k2=0;k2<8;++k2) acc[k2] += fas[(rr+2*k2)*96+kk]*wv;
    }
    __syncthreads();
  }
  float* ybuf = Ws;
  float bo = bout[c];
  #pragma unroll
  for (int k2=0;k2<8;++k2) {
    int r = rr + 2*k2;
    ybuf[r*128 + c] = acc[k2] + x[(size_t)(row0+r)*128 + c] + bo;
  }
  __syncthreads();
  int wv_ = t/64, lane = t%64;
  for (int r = wv_; r < 16; r += 4) {
    float y0 = ybuf[r*128+lane], y1 = ybuf[r*128+lane+64];
    float sum = y0+y1;
    #pragma unroll
    for (int o=1;o<64;o<<=1) sum += __shfl_xor(sum,o);
    float mean = sum * (1.0f/128.0f);
    float d0=y0-mean, d1=y1-mean;
    float vs = d0*d0+d1*d1;
    #pragma unroll
    for (int o=1;o<64;o<<=1) vs += __shfl_xor(vs,o);
    float rstd = rsqrtf(vs*(1.0f/128.0f)+1e-5f);
    x1[(size_t)(row0+r)*128+lane]    = d0*rstd*g1[lane]+b1[lane];
    x1[(size_t)(row0+r)*128+lane+64] = d1*rstd*g1[lane+64]+b1[lane+64];
  }
}

// ---------------- K5: MLP (3 layers) + residual + LN2 ----------------
__global__ __launch_bounds__(256) void k_mlp(
  const float* __restrict__ x1g,
  const float* __restrict__ Wm1,const float* __restrict__ bm1,
  const float* __restrict__ Wm2,const float* __restrict__ bm2,
  const float* __restrict__ Wm3,const float* __restrict__ bm3,
  const float* __restrict__ g2, const float* __restrict__ b2,
  float* __restrict__ out)
{
  int row0 = blockIdx.x*16;
  int t = threadIdx.x;
  __shared__ float x1s[16*128];
  __shared__ float bufA[16*128];
  __shared__ float bufB[16*128];
  __shared__ float Ws[64*128];
  for (int idx=t; idx<16*32; idx+=256)
    ((float4*)x1s)[idx] = ((const float4*)&x1g[(size_t)row0*128])[idx];
  __syncthreads();
  int c=t%128, rr=t/128;
  const float* in = x1s;
  for (int s=0;s<3;++s) {
    const float* Wcur = (s==0)?Wm1:((s==1)?Wm2:Wm3);
    const float* bcur = (s==0)?bm1:((s==1)?bm2:bm3);
    float acc[8];
    #pragma unroll
    for (int k2=0;k2<8;++k2) acc[k2]=0.f;
    for (int kc=0;kc<128;kc+=64) {
      for (int idx=t; idx<64*32; idx+=256)
        ((float4*)Ws)[idx]=((const float4*)&Wcur[(size_t)kc*128])[idx];
      __syncthreads();
      for (int kk=0;kk<64;++kk) {
        float wv=Ws[kk*128+c];
        #pragma unroll
        for (int k2=0;k2<8;++k2) acc[k2] += in[(rr+2*k2)*128 + kc+kk]*wv;
      }
      __syncthreads();
    }
    float bb = bcur[c];
    float* outb = (s%2==0) ? bufA : bufB;
    #pragma unroll
    for (int k2=0;k2<8;++k2) {
      float yv = acc[k2]+bb;
      if (s<2) yv = fmaxf(yv,0.f);
      outb[(rr+2*k2)*128+c]=yv;
    }
    __syncthreads();
    in = outb;
  }
  int wv_=t/64, lane=t%64;
  for (int r=wv_; r<16; r+=4) {
    float y0 = x1s[r*128+lane]+bufA[r*128+lane];
    float y1 = x1s[r*128+lane+64]+bufA[r*128+lane+64];
    float sum = y0+y1;
    #pragma unroll
    for (int o=1;o<64;o<<=1) sum += __shfl_xor(sum,o);
    float mean = sum * (1.0f/128.0f);
    float d0=y0-mean, d1=y1-mean;
    float vs = d0*d0+d1*d1;
    #pragma unroll
    for (int o=1;o<64;o<<=1) vs += __shfl_xor(vs,o);
    float rstd = rsqrtf(vs*(1.0f/128.0f)+1e-5f);
    out[(size_t)(row0+r)*128+lane]    = d0*rstd*g2[lane]+b2[lane];
    out[(size_t)(row0+r)*128+lane+64] = d1*rstd*g2[lane+64]+b2[lane+64];
  }
}

extern "C" void kernel_launch(void* const* d_in, const int* in_sizes, int n_in,
                              void* d_out, int out_size, void* d_ws, size_t ws_size,
                              hipStream_t stream) {
  const float* R     = (const float*)d_in[0];
  const float* coord = (const float*)d_in[1];
  const float* x     = (const float*)d_in[2];
  const float* pf    = (const float*)d_in[3];
  const float* Wq    = (const float*)d_in[5];
  const float* Wk    = (const float*)d_in[6];
  const float* Wv    = (const float*)d_in[7];
  const float* Wpb   = (const float*)d_in[8];
  const float* sc    = (const float*)d_in[9];
  const float* Wqp   = (const float*)d_in[10];
  const float* Wkp   = (const float*)d_in[11];
  const float* Wvp   = (const float*)d_in[12];
  const float* Wout  = (const float*)d_in[13];
  const float* bout  = (const float*)d_in[14];
  const float* Wm1   = (const float*)d_in[15];
  const float* bm1   = (const float*)d_in[16];
  const float* Wm2   = (const float*)d_in[17];
  const float* bm2   = (const float*)d_in[18];
  const float* Wm3   = (const float*)d_in[19];
  const float* bm3   = (const float*)d_in[20];
  const float* g1    = (const float*)d_in[21];
  const float* b1    = (const float*)d_in[22];
  const float* g2    = (const float*)d_in[23];
  const float* b2    = (const float*)d_in[24];

  float* ws = (float*)d_ws;
  float* q        = ws;                        // 2048*384
  float* k        = q + 786432;
  float* v        = k + 786432;
  float* qp       = v + 786432;                // 2048*288
  float* kp       = qp + 589824;
  float* vp       = kp + 589824;
  float* after    = vp + 589824;               // = ws + 4128768
  unsigned short* Arow = (unsigned short*)after;              // 2048*768 ush = 786432 fl
  unsigned short* Bvec = (unsigned short*)(after + 786432);
  unsigned short* Vcat = (unsigned short*)(after + 1572864);  // 786432 fl
  unsigned short* WpbT = (unsigned short*)(after + 2359296);  // 512 fl
  float* kpn      = after + 2359808;           // 24576
  float* accNV    = after + 2384384;           // 3145728
  float* accP     = after + 5530112;           // 4194304
  float* s_part   = after + 9724416;           // 49152
  float* feat_all = after + 9773568;           // 3735552
  float* x1       = accP;                      // reuse (accP dead after merge)
  float* out      = (float*)d_out;

  k_proj<<<dim3(NROW/8), dim3(256), 0, stream>>>(x,R,coord,Wq,Wk,Wv,Wqp,Wkp,Wvp,q,k,v,qp,kp,vp);
  k_pack<<<dim3(NROW/8), dim3(256), 0, stream>>>(q,k,v,qp,kp,vp,sc,Wpb,Arow,Bvec,kpn,Vcat,WpbT);
  static int attr_set = 0;
  hipFuncSetAttribute((const void*)k_attn, hipFuncAttributeMaxDynamicSharedMemorySize, 151104);
  (void)attr_set;
  k_attn<<<dim3(256), dim3(256), 151104, stream>>>(pf, Arow, Bvec, Vcat, WpbT, kpn, accNV, accP, s_part);
  k_merge<<<dim3(NROW), dim3(128), 0, stream>>>(accNV, accP, s_part, R, coord, feat_all);
  k_outproj<<<dim3(NROW/16), dim3(256), 0, stream>>>(feat_all,x,Wout,bout,g1,b1,x1);
  k_mlp<<<dim3(NROW/16), dim3(256), 0, stream>>>(x1,Wm1,bm1,Wm2,bm2,Wm3,bm3,g2,b2,out);
}

// Round 4
// 393.571 us; speedup vs baseline: 2.9157x; 1.2049x over previous
//
#include <hip/hip_runtime.h>
#include <hip/hip_bf16.h>
#include <math.h>

#define NB 4
#define LL 512
#define FF 128
#define CC 64
#define HH 12
#define DQi 32
#define PP 8
#define HD 384
#define HP3 288
#define DIN 1824
#define NROW (NB*LL)

typedef __attribute__((ext_vector_type(8))) short bf16x8;
typedef __attribute__((ext_vector_type(4))) float f32x4;

__device__ inline unsigned short f2b(float x){
  unsigned int u = __float_as_uint(x);
  unsigned int r = (u + 0x7FFFu + ((u>>16)&1u)) >> 16;
  return (unsigned short)r;
}

// ---------------- K1: projections ----------------
__global__ __launch_bounds__(256) void k_proj(
    const float* __restrict__ x, const float* __restrict__ R, const float* __restrict__ coord,
    const float* __restrict__ Wq, const float* __restrict__ Wk, const float* __restrict__ Wv,
    const float* __restrict__ Wqp, const float* __restrict__ Wkp, const float* __restrict__ Wvp,
    float* __restrict__ q, float* __restrict__ k, float* __restrict__ v,
    float* __restrict__ qp, float* __restrict__ kp, float* __restrict__ vp)
{
  const int RB = 8;
  int row0 = blockIdx.x * RB;
  int t = threadIdx.x;
  __shared__ float xs[8][FF];
  __shared__ float pl[8][3*HP3];
  for (int idx = t; idx < RB*FF/4; idx += 256) {
    int r = idx / 32, s = idx % 32;
    ((float4*)xs[r])[s] = ((const float4*)&x[(size_t)(row0+r)*FF])[s];
  }
  __syncthreads();
  for (int c = t; c < HD; c += 256) {
    float aq[8], ak[8], av[8];
    #pragma unroll
    for (int r=0;r<RB;++r){aq[r]=0.f;ak[r]=0.f;av[r]=0.f;}
    for (int f = 0; f < FF; ++f) {
      float wq = Wq[f*HD+c], wk = Wk[f*HD+c], wv = Wv[f*HD+c];
      #pragma unroll
      for (int r=0;r<RB;++r){ float xv=xs[r][f]; aq[r]+=xv*wq; ak[r]+=xv*wk; av[r]+=xv*wv; }
    }
    for (int r=0;r<RB;++r){ size_t o=(size_t)(row0+r)*HD+c; q[o]=aq[r]; k[o]=ak[r]; v[o]=av[r]; }
  }
  for (int c = t; c < HP3; c += 256) {
    float a0[8], a1[8], a2[8];
    #pragma unroll
    for (int r=0;r<RB;++r){a0[r]=0.f;a1[r]=0.f;a2[r]=0.f;}
    for (int f=0; f<FF; ++f) {
      float w0=Wqp[f*HP3+c], w1=Wkp[f*HP3+c], w2=Wvp[f*HP3+c];
      #pragma unroll
      for (int r=0;r<RB;++r){ float xv=xs[r][f]; a0[r]+=xv*w0; a1[r]+=xv*w1; a2[r]+=xv*w2; }
    }
    for (int r=0;r<RB;++r){ pl[r][c]=a0[r]; pl[r][HP3+c]=a1[r]; pl[r][2*HP3+c]=a2[r]; }
  }
  __syncthreads();
  for (int idx = t; idx < RB*3*96; idx += 256) {
    int r = idx / 288; int rem = idx % 288; int which = rem / 96; int m = rem % 96;
    int row = row0 + r;
    const float* Rl = &R[(size_t)row*9];
    float cx = coord[(size_t)row*3+0], cy = coord[(size_t)row*3+1], cz = coord[(size_t)row*3+2];
    const float* p = &pl[r][which*HP3 + m*3];
    float gg0 = Rl[0]*p[0]+Rl[1]*p[1]+Rl[2]*p[2]+cx;
    float gg1 = Rl[3]*p[0]+Rl[4]*p[1]+Rl[5]*p[2]+cy;
    float gg2 = Rl[6]*p[0]+Rl[7]*p[1]+Rl[8]*p[2]+cz;
    float* dst = which==0?qp:(which==1?kp:vp);
    size_t o = (size_t)row*HP3 + m*3;
    dst[o]=gg0; dst[o+1]=gg1; dst[o+2]=gg2;
  }
}

// ---------------- K1b: pack to bf16 MFMA-friendly layouts ----------------
__global__ __launch_bounds__(256) void k_pack(
  const float* __restrict__ q, const float* __restrict__ k, const float* __restrict__ v,
  const float* __restrict__ qp, const float* __restrict__ kp, const float* __restrict__ vp,
  const float* __restrict__ sc, const float* __restrict__ Wpb,
  unsigned short* __restrict__ Arow, unsigned short* __restrict__ Bvec,
  float* __restrict__ kpn, unsigned short* __restrict__ Vcat, unsigned short* __restrict__ WpbT)
{
  const float C3 = 0.57735026918962576f;
  const float C1C3 = 0.17677669529663687f * C3;
  int row0 = blockIdx.x * 8;
  int t = threadIdx.x;
  for (int idx = t; idx < 8*768; idx += 256) {
    int lr = idx / 768; int rem = idx % 768; int h = rem >> 6; int d = rem & 63;
    int row = row0 + lr;
    float cof = -log1pf(__expf(sc[h])) * (1.0f/12.0f);
    float av, bv;
    if (d < 32) { av = q[(size_t)row*HD + h*32 + d] * C1C3; bv = k[(size_t)row*HD + h*32 + d]; }
    else if (d < 56) { int e = d-32;
      av = qp[(size_t)row*HP3 + h*24 + e] * (-2.0f*cof*C3);
      bv = kp[(size_t)row*HP3 + h*24 + e]; }
    else { av = 0.f; bv = 0.f; }
    Arow[(size_t)row*768 + rem] = f2b(av);
    Bvec[(size_t)row*768 + rem] = f2b(bv);
  }
  for (int idx = t; idx < 96; idx += 256) {
    int lr = idx / 12, h = idx % 12; int row = row0 + lr;
    float cof = -log1pf(__expf(sc[h])) * (1.0f/12.0f);
    float ss = 0.f;
    for (int e=0;e<24;++e){ float vv = kp[(size_t)row*HP3 + h*24 + e]; ss += vv*vv; }
    kpn[(size_t)row*12 + h] = cof * C3 * ss;
  }
  int n = row0 >> 9; int j0l = row0 & 511;
  for (int idx = t; idx < 768; idx += 256) {
    int h = idx >> 6, d = idx & 63;
    unsigned short tmp[8];
    for (int lr=0; lr<8; ++lr) {
      float vv;
      if (d < 32) vv = v[(size_t)(row0+lr)*HD + h*32 + d];
      else if (d < 56) vv = vp[(size_t)(row0+lr)*HP3 + h*24 + (d-32)];
      else vv = 0.f;
      tmp[lr] = f2b(vv);
    }
    uint4 pk;
    pk.x = (unsigned)tmp[0] | ((unsigned)tmp[1]<<16);
    pk.y = (unsigned)tmp[2] | ((unsigned)tmp[3]<<16);
    pk.z = (unsigned)tmp[4] | ((unsigned)tmp[5]<<16);
    pk.w = (unsigned)tmp[6] | ((unsigned)tmp[7]<<16);
    *(uint4*)&Vcat[(((size_t)n*12 + h)*64 + d)*512 + j0l] = pk;
  }
  if (blockIdx.x == 0) {
    for (int idx = t; idx < 16*64; idx += 256) {
      int h = idx >> 6, c = idx & 63;
      WpbT[idx] = (h < HH) ? f2b(Wpb[c*HH + h] * C3) : (unsigned short)0;
    }
  }
}

// ---------------- K2: fused attention, i-tile 8, 2 blocks/CU ----------------
// grid: 512 = n(4) x ib(64) x jh(2). 256 threads.
// LDS (74880 B): pftile [8i][64c][40j-pad, i-stride 2592] bf16 | W1 [h*8+i][40] |
//                W2 [i*16+h][40] | lgP f32 [8i][32j][13pad] | kpn_s f32 [32j][12h]
#define LGP(i,j,h) ((i)*416 + (j)*13 + (h))
extern "C" __global__ void __launch_bounds__(256,2) k_attn(
  const float* __restrict__ pf, const unsigned short* __restrict__ Arow,
  const unsigned short* __restrict__ Bvec, const unsigned short* __restrict__ Vcat,
  const unsigned short* __restrict__ WpbT, const float* __restrict__ kpn,
  float* __restrict__ accNV, float* __restrict__ accP, float* __restrict__ s_part)
{
  extern __shared__ char smem_raw[];
  unsigned short* pftile = (unsigned short*)smem_raw;            // 41472 B
  unsigned short* W1 = (unsigned short*)(smem_raw + 41472);      // 8320 B  (104x40)
  unsigned short* W2 = (unsigned short*)(smem_raw + 49792);      // 10240 B (128x40)
  float* lgP   = (float*)(smem_raw + 60032);                     // 13312 B
  float* kpn_s = (float*)(smem_raw + 73344);                     // 1536 B

  int b = blockIdx.x;
  int jh = b & 1; int ib = (b >> 1) & 63; int n = b >> 7;
  int i0 = ib * 8; int jbase = jh * 256;
  int t = threadIdx.x; int w = t >> 6; int l = t & 63;
  int l15 = l & 15, lg4 = l >> 4;

  // zero W1+W2 (adjacent, 18560 B) so pad rows stay benign
  for (int idx = t; idx < 4640; idx += 256) ((unsigned*)W1)[idx] = 0u;

  bf16x8 zz;
  #pragma unroll
  for (int e=0;e<8;++e) zz[e] = 0;
  bf16x8 aAB[3][2];
  #pragma unroll
  for (int hh=0; hh<3; ++hh) {
    int h = 3*w + hh;
    #pragma unroll
    for (int ks=0; ks<2; ++ks)
      aAB[hh][ks] = (l15 < 8) ? *(const bf16x8*)&Arow[(size_t)(n*LL + i0 + l15)*768 + h*64 + ks*32 + lg4*8] : zz;
  }
  bf16x8 aPV[2];
  #pragma unroll
  for (int ks=0; ks<2; ++ks)
    aPV[ks] = *(const bf16x8*)&WpbT[l15*64 + ks*32 + lg4*8];

  f32x4 cNV[3][4]; f32x4 cP[2][4];
  #pragma unroll
  for (int a=0;a<3;++a)
    #pragma unroll
    for (int nt=0;nt<4;++nt) cNV[a][nt] = (f32x4){0.f,0.f,0.f,0.f};
  #pragma unroll
  for (int a=0;a<2;++a)
    #pragma unroll
    for (int nt=0;nt<4;++nt) cP[a][nt] = (f32x4){0.f,0.f,0.f,0.f};
  float s_acc[3][4];
  #pragma unroll
  for (int a=0;a<3;++a)
    #pragma unroll
    for (int r=0;r<4;++r) s_acc[a][r] = 0.f;

  __syncthreads();

  for (int jt = 0; jt < 8; ++jt) {
    int j0 = jbase + jt*32;
    if (t < 96) ((float4*)kpn_s)[t] = ((const float4*)(kpn + (size_t)(n*LL + j0)*12))[t];
    // ---- phase L: AB logits -> registers ----
    f32x4 cL[3][2];
    #pragma unroll
    for (int hh=0; hh<3; ++hh) {
      int h = 3*w + hh;
      cL[hh][0] = (f32x4){0.f,0.f,0.f,0.f};
      cL[hh][1] = (f32x4){0.f,0.f,0.f,0.f};
      #pragma unroll
      for (int ks=0; ks<2; ++ks) {
        bf16x8 b0 = *(const bf16x8*)&Bvec[(size_t)(n*LL + j0 + l15)*768 + h*64 + ks*32 + lg4*8];
        bf16x8 b1 = *(const bf16x8*)&Bvec[(size_t)(n*LL + j0 + 16 + l15)*768 + h*64 + ks*32 + lg4*8];
        cL[hh][0] = __builtin_amdgcn_mfma_f32_16x16x32_bf16(aAB[hh][ks], b0, cL[hh][0], 0,0,0);
        cL[hh][1] = __builtin_amdgcn_mfma_f32_16x16x32_bf16(aAB[hh][ks], b1, cL[hh][1], 0,0,0);
      }
    }
    // ---- phase P: pv from global pf; also scatter bf16 pf tile to LDS ----
    #pragma unroll
    for (int pp=0; pp<4; ++pp) {
      int p = 4*w + pp; int ii = p >> 1; int jh2 = p & 1; int jloc = jh2*16 + l15;
      const float* src = pf + ((size_t)(n*LL + i0 + ii)*LL + (j0 + jloc))*CC;
      f32x4 cpv = (f32x4){0.f,0.f,0.f,0.f};
      #pragma unroll
      for (int ks=0; ks<2; ++ks) {
        float4 va = *(const float4*)(src + ks*32 + lg4*8);
        float4 vb = *(const float4*)(src + ks*32 + lg4*8 + 4);
        bf16x8 bb;
        bb[0]=(short)f2b(va.x); bb[1]=(short)f2b(va.y); bb[2]=(short)f2b(va.z); bb[3]=(short)f2b(va.w);
        bb[4]=(short)f2b(vb.x); bb[5]=(short)f2b(vb.y); bb[6]=(short)f2b(vb.z); bb[7]=(short)f2b(vb.w);
        cpv = __builtin_amdgcn_mfma_f32_16x16x32_bf16(aPV[ks], bb, cpv, 0,0,0);
        int cbase = ks*32 + lg4*8;
        #pragma unroll
        for (int e=0;e<8;++e) pftile[ii*2592 + (cbase+e)*40 + jloc] = (unsigned short)bb[e];
      }
      #pragma unroll
      for (int r=0;r<4;++r) { int h2 = lg4*4 + r; if (h2 < HH) lgP[LGP(ii, jloc, h2)] = cpv[r]; }
    }
    __syncthreads();
    // ---- phase SM: exp in-register, write W1/W2 ----
    if (lg4 < 2) {
      #pragma unroll
      for (int hh=0; hh<3; ++hh) {
        int h = 3*w + hh;
        #pragma unroll
        for (int r=0;r<4;++r) {
          int i = lg4*4 + r;
          #pragma unroll
          for (int jh2=0; jh2<2; ++jh2) {
            int j = jh2*16 + l15;
            float lv = cL[hh][jh2][r] + lgP[LGP(i, j, h)] + kpn_s[j*12 + h];
            float e = __expf(lv);
            s_acc[hh][r] += e;
            unsigned short eb = f2b(e);
            W1[(h*8 + i)*40 + j] = eb;
            W2[(i*16 + h)*40 + j] = eb;
          }
        }
      }
    }
    __syncthreads();
    // ---- phase A: accumulate ----
    #pragma unroll
    for (int hh=0; hh<3; ++hh) {
      int h = 3*w + hh;
      bf16x8 aW = *(const bf16x8*)&W1[(h*8 + l15)*40 + lg4*8];
      #pragma unroll
      for (int nt=0; nt<4; ++nt) {
        bf16x8 bV = *(const bf16x8*)&Vcat[(((size_t)n*12 + h)*64 + nt*16 + l15)*512 + j0 + lg4*8];
        cNV[hh][nt] = __builtin_amdgcn_mfma_f32_16x16x32_bf16(aW, bV, cNV[hh][nt], 0,0,0);
      }
    }
    #pragma unroll
    for (int it=0; it<2; ++it) {
      int ii = 2*w + it;
      bf16x8 aW2 = *(const bf16x8*)&W2[(ii*16 + l15)*40 + lg4*8];
      #pragma unroll
      for (int nt=0; nt<4; ++nt) {
        bf16x8 bP = *(const bf16x8*)&pftile[ii*2592 + (nt*16 + l15)*40 + lg4*8];
        cP[it][nt] = __builtin_amdgcn_mfma_f32_16x16x32_bf16(aW2, bP, cP[it][nt], 0,0,0);
      }
    }
    __syncthreads();
  }
  // ---- epilogue ----
  #pragma unroll
  for (int hh=0; hh<3; ++hh) {
    int h = 3*w + hh;
    #pragma unroll
    for (int r=0;r<4;++r) {
      float val = s_acc[hh][r];
      #pragma unroll
      for (int o=1;o<16;o<<=1) val += __shfl_xor(val, o);
      if (lg4 < 2 && l15 == 0) {
        int i = lg4*4 + r;
        s_part[(size_t)b*96 + i*12 + h] = val;
      }
    }
  }
  if (lg4 < 2) {
    #pragma unroll
    for (int hh=0; hh<3; ++hh) {
      int h = 3*w + hh;
      #pragma unroll
      for (int nt=0; nt<4; ++nt)
        #pragma unroll
        for (int r=0;r<4;++r) {
          int ii = lg4*4 + r;
          accNV[(((size_t)b*12 + h)*8 + ii)*64 + nt*16 + l15] = cNV[hh][nt][r];
        }
    }
  }
  #pragma unroll
  for (int it=0; it<2; ++it) {
    int ii = 2*w + it;
    #pragma unroll
    for (int nt=0; nt<4; ++nt)
      #pragma unroll
      for (int r=0;r<4;++r) {
        int h2 = lg4*4 + r;
        accP[(((size_t)b*8 + ii)*16 + h2)*64 + nt*16 + l15] = cP[it][nt][r];
      }
  }
}

// ---------------- K3: merge partials -> feat_all ----------------
__global__ __launch_bounds__(128) void k_merge(
  const float* __restrict__ accNV, const float* __restrict__ accP, const float* __restrict__ s_part,
  const float* __restrict__ R, const float* __restrict__ coord,
  float* __restrict__ feat_all)
{
  int r = blockIdx.x; int t = threadIdx.x;
  int n = r >> 9; int i = r & 511; int ib = i >> 3; int iloc = i & 7;
  int b0 = n*128 + ib*2; int b1 = b0 + 1;
  __shared__ float sden[12];
  __shared__ float aggr_s[288];
  if (t < 12) sden[t] = 1.0f / (s_part[(size_t)b0*96 + iloc*12 + t] + s_part[(size_t)b1*96 + iloc*12 + t]);
  __syncthreads();
  size_t fb = (size_t)r * DIN;
  for (int idx = t; idx < 768; idx += 128) {
    int h = idx >> 6, c = idx & 63;
    float vsum = accP[(((size_t)b0*8 + iloc)*16 + h)*64 + c] + accP[(((size_t)b1*8 + iloc)*16 + h)*64 + c];
    feat_all[fb + idx] = vsum * sden[h];
  }
  for (int idx = t; idx < 384; idx += 128) {
    int h = idx >> 5, d = idx & 31;
    float vsum = accNV[(((size_t)b0*12 + h)*8 + iloc)*64 + d] + accNV[(((size_t)b1*12 + h)*8 + iloc)*64 + d];
    feat_all[fb + 768 + idx] = vsum * sden[h];
  }
  for (int idx = t; idx < 288; idx += 128) {
    int h = idx / 24, e = idx % 24;
    float vsum = accNV[(((size_t)b0*12 + h)*8 + iloc)*64 + 32 + e] + accNV[(((size_t)b1*12 + h)*8 + iloc)*64 + 32 + e];
    aggr_s[idx] = vsum * sden[h];
  }
  __syncthreads();
  for (int idx = t; idx < 96; idx += 128) {
    int h = idx >> 3, p = idx & 7;
    const float* Rl = &R[(size_t)r*9];
    float X0 = aggr_s[h*24 + p*3 + 0] - coord[(size_t)r*3 + 0];
    float X1 = aggr_s[h*24 + p*3 + 1] - coord[(size_t)r*3 + 1];
    float X2 = aggr_s[h*24 + p*3 + 2] - coord[(size_t)r*3 + 2];
    float p0 = Rl[0]*X0 + Rl[3]*X1 + Rl[6]*X2;
    float p1 = Rl[1]*X0 + Rl[4]*X1 + Rl[7]*X2;
    float p2 = Rl[2]*X0 + Rl[5]*X1 + Rl[8]*X2;
    float dist = sqrtf(p0*p0 + p1*p1 + p2*p2);
    float inv = 1.0f / (dist + 1e-4f);
    feat_all[fb + 1152 + idx*3 + 0] = p0;
    feat_all[fb + 1152 + idx*3 + 1] = p1;
    feat_all[fb + 1152 + idx*3 + 2] = p2;
    feat_all[fb + 1440 + idx] = dist;
    feat_all[fb + 1536 + idx*3 + 0] = p0*inv;
    feat_all[fb + 1536 + idx*3 + 1] = p1*inv;
    feat_all[fb + 1536 + idx*3 + 2] = p2*inv;
  }
}

// ---------------- K4: out-projection GEMM + residual + LN1 ----------------
__global__ __launch_bounds__(256) void k_outproj(
   const float* __restrict__ feat_all, const float* __restrict__ x,
   const float* __restrict__ Wout, const float* __restrict__ bout,
   const float* __restrict__ g1, const float* __restrict__ b1,
   float* __restrict__ x1)
{
  int row0 = blockIdx.x * 16;
  int t = threadIdx.x;
  __shared__ float Ws[96*128];
  __shared__ float fas[16*96];
  int c = t % 128, rr = t / 128;
  float acc[8];
  #pragma unroll
  for (int k2=0;k2<8;++k2) acc[k2]=0.f;
  for (int kc = 0; kc < DIN; kc += 96) {
    for (int idx=t; idx<96*128/4; idx+=256)
      ((float4*)Ws)[idx] = ((const float4*)&Wout[(size_t)kc*128])[idx];
    for (int idx=t; idx<16*24; idx+=256) {
      int r = idx/24, s4 = idx%24;
      ((float4*)&fas[r*96])[s4] = ((const float4*)&feat_all[(size_t)(row0+r)*DIN + kc])[s4];
    }
    __syncthreads();
    for (int kk=0; kk<96; ++kk) {
      float wv = Ws[kk*128 + c];
      #pragma unroll
      for (int k2=0;k2<8;++k2) acc[k2] += fas[(rr+2*k2)*96+kk]*wv;
    }
    __syncthreads();
  }
  float* ybuf = Ws;
  float bo = bout[c];
  #pragma unroll
  for (int k2=0;k2<8;++k2) {
    int r = rr + 2*k2;
    ybuf[r*128 + c] = acc[k2] + x[(size_t)(row0+r)*128 + c] + bo;
  }
  __syncthreads();
  int wv_ = t/64, lane = t%64;
  for (int r = wv_; r < 16; r += 4) {
    float y0 = ybuf[r*128+lane], y1 = ybuf[r*128+lane+64];
    float sum = y0+y1;
    #pragma unroll
    for (int o=1;o<64;o<<=1) sum += __shfl_xor(sum,o);
    float mean = sum * (1.0f/128.0f);
    float d0=y0-mean, d1=y1-mean;
    float vs = d0*d0+d1*d1;
    #pragma unroll
    for (int o=1;o<64;o<<=1) vs += __shfl_xor(vs,o);
    float rstd = rsqrtf(vs*(1.0f/128.0f)+1e-5f);
    x1[(size_t)(row0+r)*128+lane]    = d0*rstd*g1[lane]+b1[lane];
    x1[(size_t)(row0+r)*128+lane+64] = d1*rstd*g1[lane+64]+b1[lane+64];
  }
}

// ---------------- K5: MLP (3 layers) + residual + LN2 ----------------
__global__ __launch_bounds__(256) void k_mlp(
  const float* __restrict__ x1g,
  const float* __restrict__ Wm1,const float* __restrict__ bm1,
  const float* __restrict__ Wm2,const float* __restrict__ bm2,
  const float* __restrict__ Wm3,const float* __restrict__ bm3,
  const float* __restrict__ g2, const float* __restrict__ b2,
  float* __restrict__ out)
{
  int row0 = blockIdx.x*16;
  int t = threadIdx.x;
  __shared__ float x1s[16*128];
  __shared__ float bufA[16*128];
  __shared__ float bufB[16*128];
  __shared__ float Ws[64*128];
  for (int idx=t; idx<16*32; idx+=256)
    ((float4*)x1s)[idx] = ((const float4*)&x1g[(size_t)row0*128])[idx];
  __syncthreads();
  int c=t%128, rr=t/128;
  const float* in = x1s;
  for (int s=0;s<3;++s) {
    const float* Wcur = (s==0)?Wm1:((s==1)?Wm2:Wm3);
    const float* bcur = (s==0)?bm1:((s==1)?bm2:bm3);
    float acc[8];
    #pragma unroll
    for (int k2=0;k2<8;++k2) acc[k2]=0.f;
    for (int kc=0;kc<128;kc+=64) {
      for (int idx=t; idx<64*32; idx+=256)
        ((float4*)Ws)[idx]=((const float4*)&Wcur[(size_t)kc*128])[idx];
      __syncthreads();
      for (int kk=0;kk<64;++kk) {
        float wv=Ws[kk*128+c];
        #pragma unroll
        for (int k2=0;k2<8;++k2) acc[k2] += in[(rr+2*k2)*128 + kc+kk]*wv;
      }
      __syncthreads();
    }
    float bb = bcur[c];
    float* outb = (s%2==0) ? bufA : bufB;
    #pragma unroll
    for (int k2=0;k2<8;++k2) {
      float yv = acc[k2]+bb;
      if (s<2) yv = fmaxf(yv,0.f);
      outb[(rr+2*k2)*128+c]=yv;
    }
    __syncthreads();
    in = outb;
  }
  int wv_=t/64, lane=t%64;
  for (int r=wv_; r<16; r+=4) {
    float y0 = x1s[r*128+lane]+bufA[r*128+lane];
    float y1 = x1s[r*128+lane+64]+bufA[r*128+lane+64];
    float sum = y0+y1;
    #pragma unroll
    for (int o=1;o<64;o<<=1) sum += __shfl_xor(sum,o);
    float mean = sum * (1.0f/128.0f);
    float d0=y0-mean, d1=y1-mean;
    float vs = d0*d0+d1*d1;
    #pragma unroll
    for (int o=1;o<64;o<<=1) vs += __shfl_xor(vs,o);
    float rstd = rsqrtf(vs*(1.0f/128.0f)+1e-5f);
    out[(size_t)(row0+r)*128+lane]    = d0*rstd*g2[lane]+b2[lane];
    out[(size_t)(row0+r)*128+lane+64] = d1*rstd*g2[lane+64]+b2[lane+64];
  }
}

extern "C" void kernel_launch(void* const* d_in, const int* in_sizes, int n_in,
                              void* d_out, int out_size, void* d_ws, size_t ws_size,
                              hipStream_t stream) {
  const float* R     = (const float*)d_in[0];
  const float* coord = (const float*)d_in[1];
  const float* x     = (const float*)d_in[2];
  const float* pf    = (const float*)d_in[3];
  const float* Wq    = (const float*)d_in[5];
  const float* Wk    = (const float*)d_in[6];
  const float* Wv    = (const float*)d_in[7];
  const float* Wpb   = (const float*)d_in[8];
  const float* sc    = (const float*)d_in[9];
  const float* Wqp   = (const float*)d_in[10];
  const float* Wkp   = (const float*)d_in[11];
  const float* Wvp   = (const float*)d_in[12];
  const float* Wout  = (const float*)d_in[13];
  const float* bout  = (const float*)d_in[14];
  const float* Wm1   = (const float*)d_in[15];
  const float* bm1   = (const float*)d_in[16];
  const float* Wm2   = (const float*)d_in[17];
  const float* bm2   = (const float*)d_in[18];
  const float* Wm3   = (const float*)d_in[19];
  const float* bm3   = (const float*)d_in[20];
  const float* g1    = (const float*)d_in[21];
  const float* b1    = (const float*)d_in[22];
  const float* g2    = (const float*)d_in[23];
  const float* b2    = (const float*)d_in[24];

  float* ws = (float*)d_ws;
  float* q        = ws;
  float* k        = q + 786432;
  float* v        = k + 786432;
  float* qp       = v + 786432;
  float* kp       = qp + 589824;
  float* vp       = kp + 589824;
  float* after    = vp + 589824;
  unsigned short* Arow = (unsigned short*)after;
  unsigned short* Bvec = (unsigned short*)(after + 786432);
  unsigned short* Vcat = (unsigned short*)(after + 1572864);
  unsigned short* WpbT = (unsigned short*)(after + 2359296);
  float* kpn      = after + 2359808;
  float* accNV    = after + 2384384;           // 512*12*8*64 = 3145728
  float* accP     = after + 5530112;           // 512*8*16*64 = 4194304
  float* s_part   = after + 9724416;           // 512*96 = 49152
  float* feat_all = after + 9773568;           // 3735552
  float* x1       = accP;                      // reuse
  float* out      = (float*)d_out;

  k_proj<<<dim3(NROW/8), dim3(256), 0, stream>>>(x,R,coord,Wq,Wk,Wv,Wqp,Wkp,Wvp,q,k,v,qp,kp,vp);
  k_pack<<<dim3(NROW/8), dim3(256), 0, stream>>>(q,k,v,qp,kp,vp,sc,Wpb,Arow,Bvec,kpn,Vcat,WpbT);
  hipFuncSetAttribute((const void*)k_attn, hipFuncAttributeMaxDynamicSharedMemorySize, 74880);
  k_attn<<<dim3(512), dim3(256), 74880, stream>>>(pf, Arow, Bvec, Vcat, WpbT, kpn, accNV, accP, s_part);
  k_merge<<<dim3(NROW), dim3(128), 0, stream>>>(accNV, accP, s_part, R, coord, feat_all);
  k_outproj<<<dim3(NROW/16), dim3(256), 0, stream>>>(feat_all,x,Wout,bout,g1,b1,x1);
  k_mlp<<<dim3(NROW/16), dim3(256), 0, stream>>>(x1,Wm1,bm1,Wm2,bm2,Wm3,bm3,g2,b2,out);
}

// Round 5
// 266.774 us; speedup vs baseline: 4.3015x; 1.4753x over previous
//
#include <hip/hip_runtime.h>
#include <hip/hip_bf16.h>
#include <math.h>

#define NB 4
#define LL 512
#define FF 128
#define CC 64
#define HH 12
#define DQi 32
#define PP 8
#define HD 384
#define HP3 288
#define DIN 1824
#define NROW (NB*LL)

typedef __attribute__((ext_vector_type(8))) short bf16x8;
typedef __attribute__((ext_vector_type(4))) float f32x4;

__device__ inline unsigned short f2b(float x){
  unsigned int u = __float_as_uint(x);
  unsigned int r = (u + 0x7FFFu + ((u>>16)&1u)) >> 16;
  return (unsigned short)r;
}

// ---------------- K1: projections ----------------
__global__ __launch_bounds__(256) void k_proj(
    const float* __restrict__ x, const float* __restrict__ R, const float* __restrict__ coord,
    const float* __restrict__ Wq, const float* __restrict__ Wk, const float* __restrict__ Wv,
    const float* __restrict__ Wqp, const float* __restrict__ Wkp, const float* __restrict__ Wvp,
    float* __restrict__ q, float* __restrict__ k, float* __restrict__ v,
    float* __restrict__ qp, float* __restrict__ kp, float* __restrict__ vp)
{
  const int RB = 8;
  int row0 = blockIdx.x * RB;
  int t = threadIdx.x;
  __shared__ float xs[8][FF];
  __shared__ float pl[8][3*HP3];
  for (int idx = t; idx < RB*FF/4; idx += 256) {
    int r = idx / 32, s = idx % 32;
    ((float4*)xs[r])[s] = ((const float4*)&x[(size_t)(row0+r)*FF])[s];
  }
  __syncthreads();
  for (int c = t; c < HD; c += 256) {
    float aq[8], ak[8], av[8];
    #pragma unroll
    for (int r=0;r<RB;++r){aq[r]=0.f;ak[r]=0.f;av[r]=0.f;}
    for (int f = 0; f < FF; ++f) {
      float wq = Wq[f*HD+c], wk = Wk[f*HD+c], wv = Wv[f*HD+c];
      #pragma unroll
      for (int r=0;r<RB;++r){ float xv=xs[r][f]; aq[r]+=xv*wq; ak[r]+=xv*wk; av[r]+=xv*wv; }
    }
    for (int r=0;r<RB;++r){ size_t o=(size_t)(row0+r)*HD+c; q[o]=aq[r]; k[o]=ak[r]; v[o]=av[r]; }
  }
  for (int c = t; c < HP3; c += 256) {
    float a0[8], a1[8], a2[8];
    #pragma unroll
    for (int r=0;r<RB;++r){a0[r]=0.f;a1[r]=0.f;a2[r]=0.f;}
    for (int f=0; f<FF; ++f) {
      float w0=Wqp[f*HP3+c], w1=Wkp[f*HP3+c], w2=Wvp[f*HP3+c];
      #pragma unroll
      for (int r=0;r<RB;++r){ float xv=xs[r][f]; a0[r]+=xv*w0; a1[r]+=xv*w1; a2[r]+=xv*w2; }
    }
    for (int r=0;r<RB;++r){ pl[r][c]=a0[r]; pl[r][HP3+c]=a1[r]; pl[r][2*HP3+c]=a2[r]; }
  }
  __syncthreads();
  for (int idx = t; idx < RB*3*96; idx += 256) {
    int r = idx / 288; int rem = idx % 288; int which = rem / 96; int m = rem % 96;
    int row = row0 + r;
    const float* Rl = &R[(size_t)row*9];
    float cx = coord[(size_t)row*3+0], cy = coord[(size_t)row*3+1], cz = coord[(size_t)row*3+2];
    const float* p = &pl[r][which*HP3 + m*3];
    float gg0 = Rl[0]*p[0]+Rl[1]*p[1]+Rl[2]*p[2]+cx;
    float gg1 = Rl[3]*p[0]+Rl[4]*p[1]+Rl[5]*p[2]+cy;
    float gg2 = Rl[6]*p[0]+Rl[7]*p[1]+Rl[8]*p[2]+cz;
    float* dst = which==0?qp:(which==1?kp:vp);
    size_t o = (size_t)row*HP3 + m*3;
    dst[o]=gg0; dst[o+1]=gg1; dst[o+2]=gg2;
  }
}

// ---------------- K1b: pack to bf16 MFMA-friendly layouts ----------------
__global__ __launch_bounds__(256) void k_pack(
  const float* __restrict__ q, const float* __restrict__ k, const float* __restrict__ v,
  const float* __restrict__ qp, const float* __restrict__ kp, const float* __restrict__ vp,
  const float* __restrict__ sc, const float* __restrict__ Wpb,
  unsigned short* __restrict__ Arow, unsigned short* __restrict__ Bvec,
  float* __restrict__ kpn, unsigned short* __restrict__ Vcat, unsigned short* __restrict__ WpbT)
{
  const float C3 = 0.57735026918962576f;
  const float C1C3 = 0.17677669529663687f * C3;
  int row0 = blockIdx.x * 8;
  int t = threadIdx.x;
  for (int idx = t; idx < 8*768; idx += 256) {
    int lr = idx / 768; int rem = idx % 768; int h = rem >> 6; int d = rem & 63;
    int row = row0 + lr;
    float cof = -log1pf(__expf(sc[h])) * (1.0f/12.0f);
    float av, bv;
    if (d < 32) { av = q[(size_t)row*HD + h*32 + d] * C1C3; bv = k[(size_t)row*HD + h*32 + d]; }
    else if (d < 56) { int e = d-32;
      av = qp[(size_t)row*HP3 + h*24 + e] * (-2.0f*cof*C3);
      bv = kp[(size_t)row*HP3 + h*24 + e]; }
    else { av = 0.f; bv = 0.f; }
    Arow[(size_t)row*768 + rem] = f2b(av);
    Bvec[(size_t)row*768 + rem] = f2b(bv);
  }
  for (int idx = t; idx < 96; idx += 256) {
    int lr = idx / 12, h = idx % 12; int row = row0 + lr;
    float cof = -log1pf(__expf(sc[h])) * (1.0f/12.0f);
    float ss = 0.f;
    for (int e=0;e<24;++e){ float vv = kp[(size_t)row*HP3 + h*24 + e]; ss += vv*vv; }
    kpn[(size_t)row*12 + h] = cof * C3 * ss;
  }
  int n = row0 >> 9; int j0l = row0 & 511;
  for (int idx = t; idx < 768; idx += 256) {
    int h = idx >> 6, d = idx & 63;
    unsigned short tmp[8];
    for (int lr=0; lr<8; ++lr) {
      float vv;
      if (d < 32) vv = v[(size_t)(row0+lr)*HD + h*32 + d];
      else if (d < 56) vv = vp[(size_t)(row0+lr)*HP3 + h*24 + (d-32)];
      else vv = 0.f;
      tmp[lr] = f2b(vv);
    }
    uint4 pk;
    pk.x = (unsigned)tmp[0] | ((unsigned)tmp[1]<<16);
    pk.y = (unsigned)tmp[2] | ((unsigned)tmp[3]<<16);
    pk.z = (unsigned)tmp[4] | ((unsigned)tmp[5]<<16);
    pk.w = (unsigned)tmp[6] | ((unsigned)tmp[7]<<16);
    *(uint4*)&Vcat[(((size_t)n*12 + h)*64 + d)*512 + j0l] = pk;
  }
  if (blockIdx.x == 0) {
    for (int idx = t; idx < 16*64; idx += 256) {
      int h = idx >> 6, c = idx & 63;
      WpbT[idx] = (h < HH) ? f2b(Wpb[c*HH + h] * C3) : (unsigned short)0;
    }
  }
}

// ---------------- K1c: transpose out-proj / MLP weights to bf16 [col][k] ----------------
__global__ __launch_bounds__(256) void k_packW(
  const float* __restrict__ Wout, const float* __restrict__ Wm1,
  const float* __restrict__ Wm2, const float* __restrict__ Wm3,
  unsigned short* __restrict__ WoutT, unsigned short* __restrict__ WmT)
{
  int b = blockIdx.x; int t = threadIdx.x;
  if (b < 128) {
    for (int k = t; k < DIN; k += 256)
      WoutT[(size_t)b*DIN + k] = f2b(Wout[(size_t)k*128 + b]);
  } else {
    int c = b - 128;
    #pragma unroll
    for (int s=0;s<3;++s) {
      const float* Wl = (s==0)?Wm1:((s==1)?Wm2:Wm3);
      if (t < 128) WmT[(s*128 + c)*128 + t] = f2b(Wl[(size_t)t*128 + c]);
    }
  }
}

// ---------------- K2: fused attention, i-tile 8, 2 blocks/CU ----------------
#define LGP(i,j,h) ((i)*416 + (j)*13 + (h))
extern "C" __global__ void __launch_bounds__(256,2) k_attn(
  const float* __restrict__ pf, const unsigned short* __restrict__ Arow,
  const unsigned short* __restrict__ Bvec, const unsigned short* __restrict__ Vcat,
  const unsigned short* __restrict__ WpbT, const float* __restrict__ kpn,
  float* __restrict__ accNV, float* __restrict__ accP, float* __restrict__ s_part)
{
  extern __shared__ char smem_raw[];
  unsigned short* pftile = (unsigned short*)smem_raw;            // 41472 B
  unsigned short* W1 = (unsigned short*)(smem_raw + 41472);      // 8320 B  (104x40)
  unsigned short* W2 = (unsigned short*)(smem_raw + 49792);      // 10240 B (128x40)
  float* lgP   = (float*)(smem_raw + 60032);                     // 13312 B
  float* kpn_s = (float*)(smem_raw + 73344);                     // 1536 B

  int b = blockIdx.x;
  int jh = b & 1; int ib = (b >> 1) & 63; int n = b >> 7;
  int i0 = ib * 8; int jbase = jh * 256;
  int t = threadIdx.x; int w = t >> 6; int l = t & 63;
  int l15 = l & 15, lg4 = l >> 4;

  for (int idx = t; idx < 4640; idx += 256) ((unsigned*)W1)[idx] = 0u;

  bf16x8 zz;
  #pragma unroll
  for (int e=0;e<8;++e) zz[e] = 0;
  bf16x8 aAB[3][2];
  #pragma unroll
  for (int hh=0; hh<3; ++hh) {
    int h = 3*w + hh;
    #pragma unroll
    for (int ks=0; ks<2; ++ks)
      aAB[hh][ks] = (l15 < 8) ? *(const bf16x8*)&Arow[(size_t)(n*LL + i0 + l15)*768 + h*64 + ks*32 + lg4*8] : zz;
  }
  bf16x8 aPV[2];
  #pragma unroll
  for (int ks=0; ks<2; ++ks)
    aPV[ks] = *(const bf16x8*)&WpbT[l15*64 + ks*32 + lg4*8];

  f32x4 cNV[3][4]; f32x4 cP[2][4];
  #pragma unroll
  for (int a=0;a<3;++a)
    #pragma unroll
    for (int nt=0;nt<4;++nt) cNV[a][nt] = (f32x4){0.f,0.f,0.f,0.f};
  #pragma unroll
  for (int a=0;a<2;++a)
    #pragma unroll
    for (int nt=0;nt<4;++nt) cP[a][nt] = (f32x4){0.f,0.f,0.f,0.f};
  float s_acc[3][4];
  #pragma unroll
  for (int a=0;a<3;++a)
    #pragma unroll
    for (int r=0;r<4;++r) s_acc[a][r] = 0.f;

  __syncthreads();

  for (int jt = 0; jt < 8; ++jt) {
    int j0 = jbase + jt*32;
    if (t < 96) ((float4*)kpn_s)[t] = ((const float4*)(kpn + (size_t)(n*LL + j0)*12))[t];
    f32x4 cL[3][2];
    #pragma unroll
    for (int hh=0; hh<3; ++hh) {
      int h = 3*w + hh;
      cL[hh][0] = (f32x4){0.f,0.f,0.f,0.f};
      cL[hh][1] = (f32x4){0.f,0.f,0.f,0.f};
      #pragma unroll
      for (int ks=0; ks<2; ++ks) {
        bf16x8 b0 = *(const bf16x8*)&Bvec[(size_t)(n*LL + j0 + l15)*768 + h*64 + ks*32 + lg4*8];
        bf16x8 b1 = *(const bf16x8*)&Bvec[(size_t)(n*LL + j0 + 16 + l15)*768 + h*64 + ks*32 + lg4*8];
        cL[hh][0] = __builtin_amdgcn_mfma_f32_16x16x32_bf16(aAB[hh][ks], b0, cL[hh][0], 0,0,0);
        cL[hh][1] = __builtin_amdgcn_mfma_f32_16x16x32_bf16(aAB[hh][ks], b1, cL[hh][1], 0,0,0);
      }
    }
    #pragma unroll
    for (int pp=0; pp<4; ++pp) {
      int p = 4*w + pp; int ii = p >> 1; int jh2 = p & 1; int jloc = jh2*16 + l15;
      const float* src = pf + ((size_t)(n*LL + i0 + ii)*LL + (j0 + jloc))*CC;
      f32x4 cpv = (f32x4){0.f,0.f,0.f,0.f};
      #pragma unroll
      for (int ks=0; ks<2; ++ks) {
        float4 va = *(const float4*)(src + ks*32 + lg4*8);
        float4 vb = *(const float4*)(src + ks*32 + lg4*8 + 4);
        bf16x8 bb;
        bb[0]=(short)f2b(va.x); bb[1]=(short)f2b(va.y); bb[2]=(short)f2b(va.z); bb[3]=(short)f2b(va.w);
        bb[4]=(short)f2b(vb.x); bb[5]=(short)f2b(vb.y); bb[6]=(short)f2b(vb.z); bb[7]=(short)f2b(vb.w);
        cpv = __builtin_amdgcn_mfma_f32_16x16x32_bf16(aPV[ks], bb, cpv, 0,0,0);
        int cbase = ks*32 + lg4*8;
        #pragma unroll
        for (int e=0;e<8;++e) pftile[ii*2592 + (cbase+e)*40 + jloc] = (unsigned short)bb[e];
      }
      #pragma unroll
      for (int r=0;r<4;++r) { int h2 = lg4*4 + r; if (h2 < HH) lgP[LGP(ii, jloc, h2)] = cpv[r]; }
    }
    __syncthreads();
    if (lg4 < 2) {
      #pragma unroll
      for (int hh=0; hh<3; ++hh) {
        int h = 3*w + hh;
        #pragma unroll
        for (int r=0;r<4;++r) {
          int i = lg4*4 + r;
          #pragma unroll
          for (int jh2=0; jh2<2; ++jh2) {
            int j = jh2*16 + l15;
            float lv = cL[hh][jh2][r] + lgP[LGP(i, j, h)] + kpn_s[j*12 + h];
            float e = __expf(lv);
            s_acc[hh][r] += e;
            unsigned short eb = f2b(e);
            W1[(h*8 + i)*40 + j] = eb;
            W2[(i*16 + h)*40 + j] = eb;
          }
        }
      }
    }
    __syncthreads();
    #pragma unroll
    for (int hh=0; hh<3; ++hh) {
      int h = 3*w + hh;
      bf16x8 aW = *(const bf16x8*)&W1[(h*8 + l15)*40 + lg4*8];
      #pragma unroll
      for (int nt=0; nt<4; ++nt) {
        bf16x8 bV = *(const bf16x8*)&Vcat[(((size_t)n*12 + h)*64 + nt*16 + l15)*512 + j0 + lg4*8];
        cNV[hh][nt] = __builtin_amdgcn_mfma_f32_16x16x32_bf16(aW, bV, cNV[hh][nt], 0,0,0);
      }
    }
    #pragma unroll
    for (int it=0; it<2; ++it) {
      int ii = 2*w + it;
      bf16x8 aW2 = *(const bf16x8*)&W2[(ii*16 + l15)*40 + lg4*8];
      #pragma unroll
      for (int nt=0; nt<4; ++nt) {
        bf16x8 bP = *(const bf16x8*)&pftile[ii*2592 + (nt*16 + l15)*40 + lg4*8];
        cP[it][nt] = __builtin_amdgcn_mfma_f32_16x16x32_bf16(aW2, bP, cP[it][nt], 0,0,0);
      }
    }
    __syncthreads();
  }
  #pragma unroll
  for (int hh=0; hh<3; ++hh) {
    int h = 3*w + hh;
    #pragma unroll
    for (int r=0;r<4;++r) {
      float val = s_acc[hh][r];
      #pragma unroll
      for (int o=1;o<16;o<<=1) val += __shfl_xor(val, o);
      if (lg4 < 2 && l15 == 0) {
        int i = lg4*4 + r;
        s_part[(size_t)b*96 + i*12 + h] = val;
      }
    }
  }
  if (lg4 < 2) {
    #pragma unroll
    for (int hh=0; hh<3; ++hh) {
      int h = 3*w + hh;
      #pragma unroll
      for (int nt=0; nt<4; ++nt)
        #pragma unroll
        for (int r=0;r<4;++r) {
          int ii = lg4*4 + r;
          accNV[(((size_t)b*12 + h)*8 + ii)*64 + nt*16 + l15] = cNV[hh][nt][r];
        }
    }
  }
  #pragma unroll
  for (int it=0; it<2; ++it) {
    int ii = 2*w + it;
    #pragma unroll
    for (int nt=0; nt<4; ++nt)
      #pragma unroll
      for (int r=0;r<4;++r) {
        int h2 = lg4*4 + r;
        accP[(((size_t)b*8 + ii)*16 + h2)*64 + nt*16 + l15] = cP[it][nt][r];
      }
  }
}

// ---------------- K3: merge partials -> feat (bf16) ----------------
__global__ __launch_bounds__(128) void k_merge(
  const float* __restrict__ accNV, const float* __restrict__ accP, const float* __restrict__ s_part,
  const float* __restrict__ R, const float* __restrict__ coord,
  unsigned short* __restrict__ featb)
{
  int r = blockIdx.x; int t = threadIdx.x;
  int n = r >> 9; int i = r & 511; int ib = i >> 3; int iloc = i & 7;
  int b0 = n*128 + ib*2; int b1 = b0 + 1;
  __shared__ float sden[12];
  __shared__ float aggr_s[288];
  if (t < 12) sden[t] = 1.0f / (s_part[(size_t)b0*96 + iloc*12 + t] + s_part[(size_t)b1*96 + iloc*12 + t]);
  __syncthreads();
  size_t fb = (size_t)r * DIN;
  for (int idx = t; idx < 768; idx += 128) {
    int h = idx >> 6, c = idx & 63;
    float vsum = accP[(((size_t)b0*8 + iloc)*16 + h)*64 + c] + accP[(((size_t)b1*8 + iloc)*16 + h)*64 + c];
    featb[fb + idx] = f2b(vsum * sden[h]);
  }
  for (int idx = t; idx < 384; idx += 128) {
    int h = idx >> 5, d = idx & 31;
    float vsum = accNV[(((size_t)b0*12 + h)*8 + iloc)*64 + d] + accNV[(((size_t)b1*12 + h)*8 + iloc)*64 + d];
    featb[fb + 768 + idx] = f2b(vsum * sden[h]);
  }
  for (int idx = t; idx < 288; idx += 128) {
    int h = idx / 24, e = idx % 24;
    float vsum = accNV[(((size_t)b0*12 + h)*8 + iloc)*64 + 32 + e] + accNV[(((size_t)b1*12 + h)*8 + iloc)*64 + 32 + e];
    aggr_s[idx] = vsum * sden[h];
  }
  __syncthreads();
  for (int idx = t; idx < 96; idx += 128) {
    int h = idx >> 3, p = idx & 7;
    const float* Rl = &R[(size_t)r*9];
    float X0 = aggr_s[h*24 + p*3 + 0] - coord[(size_t)r*3 + 0];
    float X1 = aggr_s[h*24 + p*3 + 1] - coord[(size_t)r*3 + 1];
    float X2 = aggr_s[h*24 + p*3 + 2] - coord[(size_t)r*3 + 2];
    float p0 = Rl[0]*X0 + Rl[3]*X1 + Rl[6]*X2;
    float p1 = Rl[1]*X0 + Rl[4]*X1 + Rl[7]*X2;
    float p2 = Rl[2]*X0 + Rl[5]*X1 + Rl[8]*X2;
    float dist = sqrtf(p0*p0 + p1*p1 + p2*p2);
    float inv = 1.0f / (dist + 1e-4f);
    featb[fb + 1152 + idx*3 + 0] = f2b(p0);
    featb[fb + 1152 + idx*3 + 1] = f2b(p1);
    featb[fb + 1152 + idx*3 + 2] = f2b(p2);
    featb[fb + 1440 + idx] = f2b(dist);
    featb[fb + 1536 + idx*3 + 0] = f2b(p0*inv);
    featb[fb + 1536 + idx*3 + 1] = f2b(p1*inv);
    featb[fb + 1536 + idx*3 + 2] = f2b(p2*inv);
  }
}

// ---------------- K4: fused outproj + LN1 + MLP + LN2 (MFMA) ----------------
// grid 256 blocks x 8 rows, 256 threads = 4 waves; wave w -> cols [w*32, w*32+32)
__global__ __launch_bounds__(256) void k_head(
  const unsigned short* __restrict__ featb, const float* __restrict__ x,
  const unsigned short* __restrict__ WoutT, const float* __restrict__ bout,
  const float* __restrict__ g1, const float* __restrict__ b1,
  const unsigned short* __restrict__ WmT,
  const float* __restrict__ bm1, const float* __restrict__ bm2, const float* __restrict__ bm3,
  const float* __restrict__ g2, const float* __restrict__ b2,
  float* __restrict__ out)
{
  __shared__ float ybuf[8*128];
  __shared__ float x1f[8*128];
  __shared__ unsigned short x1b[8*136];
  __shared__ unsigned short hbA[8*136];
  __shared__ unsigned short hbB[8*136];
  int row0 = blockIdx.x * 8;
  int t = threadIdx.x; int w = t >> 6; int l = t & 63;
  int l15 = l & 15, lg4 = l >> 4;

  // ---- out-projection: 8 rows x 128 cols, K=1824 ----
  f32x4 acc0 = (f32x4){0.f,0.f,0.f,0.f}, acc1 = (f32x4){0.f,0.f,0.f,0.f};
  const unsigned short* ap  = featb + (size_t)(row0 + (l15 & 7))*DIN + lg4*8;
  const unsigned short* bp0 = WoutT + (size_t)(w*32 + l15)*DIN + lg4*8;
  const unsigned short* bp1 = bp0 + 16*DIN;
  for (int ks = 0; ks < 57; ++ks) {
    bf16x8 a  = *(const bf16x8*)(ap  + ks*32);
    bf16x8 b0 = *(const bf16x8*)(bp0 + ks*32);
    bf16x8 b1v= *(const bf16x8*)(bp1 + ks*32);
    acc0 = __builtin_amdgcn_mfma_f32_16x16x32_bf16(a, b0, acc0, 0,0,0);
    acc1 = __builtin_amdgcn_mfma_f32_16x16x32_bf16(a, b1v, acc1, 0,0,0);
  }
  #pragma unroll
  for (int r=0;r<4;++r) {
    int m = lg4*4 + r;
    if (m < 8) {
      ybuf[m*128 + w*32 + l15]      = acc0[r];
      ybuf[m*128 + w*32 + 16 + l15] = acc1[r];
    }
  }
  __syncthreads();

  // ---- LN1 (+residual x, +bout) ----
  int row = t >> 5, j = t & 31; int grow = row0 + row;
  {
    float y[4];
    #pragma unroll
    for (int c4=0;c4<4;++c4) {
      int c = j + c4*32;
      y[c4] = ybuf[row*128 + c] + x[(size_t)grow*128 + c] + bout[c];
    }
    float sum = y[0]+y[1]+y[2]+y[3];
    #pragma unroll
    for (int o=1;o<32;o<<=1) sum += __shfl_xor(sum, o);
    float mean = sum * (1.0f/128.0f);
    float vs = 0.f;
    #pragma unroll
    for (int c4=0;c4<4;++c4){ y[c4] -= mean; vs += y[c4]*y[c4]; }
    #pragma unroll
    for (int o=1;o<32;o<<=1) vs += __shfl_xor(vs, o);
    float rstd = rsqrtf(vs*(1.0f/128.0f) + 1e-5f);
    #pragma unroll
    for (int c4=0;c4<4;++c4) {
      int c = j + c4*32;
      float xv = y[c4]*rstd*g1[c] + b1[c];
      x1f[row*128 + c] = xv;
      x1b[row*136 + c] = f2b(xv);
    }
  }
  __syncthreads();

  // ---- MLP: 3 layers of 128x128 ----
  #pragma unroll
  for (int s=0; s<3; ++s) {
    const unsigned short* Ab = (s==0)? x1b : ((s==1)? hbA : hbB);
    const float* bm = (s==0)? bm1 : ((s==1)? bm2 : bm3);
    const unsigned short* Wl = WmT + s*16384;
    f32x4 a0 = (f32x4){0.f,0.f,0.f,0.f}, a1 = (f32x4){0.f,0.f,0.f,0.f};
    #pragma unroll
    for (int ks=0; ks<4; ++ks) {
      bf16x8 a = *(const bf16x8*)&Ab[(l15 & 7)*136 + ks*32 + lg4*8];
      bf16x8 b0 = *(const bf16x8*)&Wl[(size_t)(w*32 + l15)*128 + ks*32 + lg4*8];
      bf16x8 b1v = *(const bf16x8*)&Wl[(size_t)(w*32 + 16 + l15)*128 + ks*32 + lg4*8];
      a0 = __builtin_amdgcn_mfma_f32_16x16x32_bf16(a, b0, a0, 0,0,0);
      a1 = __builtin_amdgcn_mfma_f32_16x16x32_bf16(a, b1v, a1, 0,0,0);
    }
    unsigned short* Nb = (s==0)? hbA : hbB;
    #pragma unroll
    for (int r=0;r<4;++r) {
      int m = lg4*4 + r;
      if (m < 8) {
        int c0 = w*32 + l15, c1 = w*32 + 16 + l15;
        float y0 = a0[r] + bm[c0];
        float y1 = a1[r] + bm[c1];
        if (s < 2) {
          Nb[m*136 + c0] = f2b(fmaxf(y0, 0.f));
          Nb[m*136 + c1] = f2b(fmaxf(y1, 0.f));
        } else {
          ybuf[m*128 + c0] = y0;
          ybuf[m*128 + c1] = y1;
        }
      }
    }
    __syncthreads();
  }

  // ---- LN2 (+residual x1) ----
  {
    float y[4];
    #pragma unroll
    for (int c4=0;c4<4;++c4) {
      int c = j + c4*32;
      y[c4] = x1f[row*128 + c] + ybuf[row*128 + c];
    }
    float sum = y[0]+y[1]+y[2]+y[3];
    #pragma unroll
    for (int o=1;o<32;o<<=1) sum += __shfl_xor(sum, o);
    float mean = sum * (1.0f/128.0f);
    float vs = 0.f;
    #pragma unroll
    for (int c4=0;c4<4;++c4){ y[c4] -= mean; vs += y[c4]*y[c4]; }
    #pragma unroll
    for (int o=1;o<32;o<<=1) vs += __shfl_xor(vs, o);
    float rstd = rsqrtf(vs*(1.0f/128.0f) + 1e-5f);
    #pragma unroll
    for (int c4=0;c4<4;++c4) {
      int c = j + c4*32;
      out[(size_t)grow*128 + c] = y[c4]*rstd*g2[c] + b2[c];
    }
  }
}

extern "C" void kernel_launch(void* const* d_in, const int* in_sizes, int n_in,
                              void* d_out, int out_size, void* d_ws, size_t ws_size,
                              hipStream_t stream) {
  const float* R     = (const float*)d_in[0];
  const float* coord = (const float*)d_in[1];
  const float* x     = (const float*)d_in[2];
  const float* pf    = (const float*)d_in[3];
  const float* Wq    = (const float*)d_in[5];
  const float* Wk    = (const float*)d_in[6];
  const float* Wv    = (const float*)d_in[7];
  const float* Wpb   = (const float*)d_in[8];
  const float* sc    = (const float*)d_in[9];
  const float* Wqp   = (const float*)d_in[10];
  const float* Wkp   = (const float*)d_in[11];
  const float* Wvp   = (const float*)d_in[12];
  const float* Wout  = (const float*)d_in[13];
  const float* bout  = (const float*)d_in[14];
  const float* Wm1   = (const float*)d_in[15];
  const float* bm1   = (const float*)d_in[16];
  const float* Wm2   = (const float*)d_in[17];
  const float* bm2   = (const float*)d_in[18];
  const float* Wm3   = (const float*)d_in[19];
  const float* bm3   = (const float*)d_in[20];
  const float* g1    = (const float*)d_in[21];
  const float* b1    = (const float*)d_in[22];
  const float* g2    = (const float*)d_in[23];
  const float* b2    = (const float*)d_in[24];

  float* ws = (float*)d_ws;
  float* q        = ws;
  float* k        = q + 786432;
  float* v        = k + 786432;
  float* qp       = v + 786432;
  float* kp       = qp + 589824;
  float* vp       = kp + 589824;
  float* after    = vp + 589824;
  unsigned short* Arow = (unsigned short*)after;
  unsigned short* Bvec = (unsigned short*)(after + 786432);
  unsigned short* Vcat = (unsigned short*)(after + 1572864);
  unsigned short* WpbT = (unsigned short*)(after + 2359296);
  float* kpn      = after + 2359808;
  float* accNV    = after + 2384384;           // 512*12*8*64 = 3145728
  float* accP     = after + 5530112;           // 512*8*16*64 = 4194304
  float* s_part   = after + 9724416;           // 49152
  unsigned short* featb = (unsigned short*)(after + 9773568);   // 2048*1824 ush = 1867776 fl
  unsigned short* WoutT = (unsigned short*)(after + 9773568 + 1867776);  // 116736 fl
  unsigned short* WmT   = (unsigned short*)(after + 9773568 + 1867776 + 116736); // 24576 fl
  float* out      = (float*)d_out;

  k_proj<<<dim3(NROW/8), dim3(256), 0, stream>>>(x,R,coord,Wq,Wk,Wv,Wqp,Wkp,Wvp,q,k,v,qp,kp,vp);
  k_pack<<<dim3(NROW/8), dim3(256), 0, stream>>>(q,k,v,qp,kp,vp,sc,Wpb,Arow,Bvec,kpn,Vcat,WpbT);
  k_packW<<<dim3(256), dim3(256), 0, stream>>>(Wout,Wm1,Wm2,Wm3,WoutT,WmT);
  hipFuncSetAttribute((const void*)k_attn, hipFuncAttributeMaxDynamicSharedMemorySize, 74880);
  k_attn<<<dim3(512), dim3(256), 74880, stream>>>(pf, Arow, Bvec, Vcat, WpbT, kpn, accNV, accP, s_part);
  k_merge<<<dim3(NROW), dim3(128), 0, stream>>>(accNV, accP, s_part, R, coord, featb);
  k_head<<<dim3(NROW/8), dim3(256), 0, stream>>>(featb, x, WoutT, bout, g1, b1, WmT, bm1, bm2, bm3, g2, b2, out);
}